// Round 9
// baseline (3114.111 us; speedup 1.0000x reference)
//
#include <hip/hip_runtime.h>
#include <cstddef>
#include <cstdint>

#define N_NODES  200000
#define N_EDGES  3200000
#define N_GRAPHS 2000
#define BN_EPS   1e-5f
#define NB       391          // ceil(N / 512) buckets
#define BSH      9            // bucket = dst >> 9 (512 nodes per bucket)
#define CHUNK    16384        // edges per block in hist/scatter

typedef unsigned int   u32;
typedef unsigned short u16;

using short8   = __attribute__((ext_vector_type(8))) short;
using floatx16 = __attribute__((ext_vector_type(16))) float;

// ---------------------------------------------------------------------------
// bf16 helpers (raw-bit, RNE pack)
// ---------------------------------------------------------------------------
__device__ __forceinline__ float bflo(u32 v) { union {u32 i; float f;} c; c.i = v << 16; return c.f; }
__device__ __forceinline__ float bfhi(u32 v) { union {u32 i; float f;} c; c.i = v & 0xffff0000u; return c.f; }
__device__ __forceinline__ float bf1(u16 v)  { union {u32 i; float f;} c; c.i = ((u32)v) << 16; return c.f; }
__device__ __forceinline__ u32 f2bf(float f) {
    union {float f; u32 i;} c; c.f = f;
    return (c.i + 0x7fffu + ((c.i >> 16) & 1u)) >> 16;
}
__device__ __forceinline__ u32 pack2(float a, float b) { return f2bf(a) | (f2bf(b) << 16); }

// ---------------------------------------------------------------------------
// x (fp32) -> bf16
// ---------------------------------------------------------------------------
__global__ void x2bf_kernel(const float* __restrict__ x, u16* __restrict__ xb, int total4) {
    for (int i = blockIdx.x * 256 + threadIdx.x; i < total4; i += gridDim.x * 256) {
        float4 v = ((const float4*)x)[i];
        uint2 o; o.x = pack2(v.x, v.y); o.y = pack2(v.z, v.w);
        ((uint2*)xb)[i] = o;
    }
}

// ---------------------------------------------------------------------------
// W pack (all 6 layers in one launch): fp32 -> transposed K-chunked hi/lo bf16
// ---------------------------------------------------------------------------
__global__ void wpack_all(const float* __restrict__ convW, const float* __restrict__ convWlast,
                          u16* __restrict__ whi, u16* __restrict__ wlo) {
    const int PER = 384 * 128;
    int tid = blockIdx.x * 256 + threadIdx.x;
    float w;
    int dst;
    if (tid < 5 * PER) {
        int l = tid / PER, r = tid % PER;
        int k = r / 128, nn = r % 128;
        w = convW[tid];
        dst = l * PER + (k >> 6) * 128 * 64 + nn * 64 + (k & 63);
    } else {
        int r = tid - 5 * PER;
        if (r >= 384 * 64) return;
        int k = r / 64, nn = r % 64;
        w = convWlast[r];
        dst = 5 * PER + (k >> 6) * 64 * 64 + nn * 64 + (k & 63);
    }
    u16 hi = (u16)f2bf(w);
    float rem = w - bf1(hi);
    whi[dst] = hi;
    wlo[dst] = (u16)f2bf(rem);
}

// ---------------------------------------------------------------------------
// CSR build via 391-bucket multisplit (bucket = dst >> 9)
// ---------------------------------------------------------------------------
__global__ __launch_bounds__(256)
void bucket_hist(const int* __restrict__ edst, int* __restrict__ bcnt, int e) {
    __shared__ int h[NB];
    for (int t = threadIdx.x; t < NB; t += 256) h[t] = 0;
    __syncthreads();
    int base = blockIdx.x * CHUNK;
    int end  = min(base + CHUNK, e);
    for (int i = base + threadIdx.x; i < end; i += 256)
        atomicAdd(&h[edst[i] >> BSH], 1);
    __syncthreads();
    for (int t = threadIdx.x; t < NB; t += 256)
        if (h[t]) atomicAdd(&bcnt[t], h[t]);
}

__global__ void bucket_scan(const int* __restrict__ bcnt, int* __restrict__ bbase,
                            int* __restrict__ bcur) {
    __shared__ int ls[512];
    int t = threadIdx.x;
    int v = (t < NB) ? bcnt[t] : 0;
    ls[t] = v;
    __syncthreads();
    for (int off = 1; off < 512; off <<= 1) {
        int a = (t >= off) ? ls[t - off] : 0;
        __syncthreads();
        ls[t] += a;
        __syncthreads();
    }
    if (t <= NB) {
        int excl = ls[t] - v;
        bbase[t] = excl;
        if (t < NB) bcur[t] = excl;
    }
}

__global__ __launch_bounds__(256)
void bucket_scatter(const int* __restrict__ esrc, const int* __restrict__ edst,
                    int* __restrict__ bcur, uint2* __restrict__ esorted, int e) {
    __shared__ int h[NB], lbase[NB], lcur[NB];
    for (int t = threadIdx.x; t < NB; t += 256) { h[t] = 0; lcur[t] = 0; }
    __syncthreads();
    int base = blockIdx.x * CHUNK;
    int end  = min(base + CHUNK, e);
    for (int i = base + threadIdx.x; i < end; i += 256)
        atomicAdd(&h[edst[i] >> BSH], 1);
    __syncthreads();
    for (int t = threadIdx.x; t < NB; t += 256)
        lbase[t] = h[t] ? atomicAdd(&bcur[t], h[t]) : 0;
    __syncthreads();
    for (int i = base + threadIdx.x; i < end; i += 256) {
        int d = edst[i];
        int b = d >> BSH;
        int p = lbase[b] + atomicAdd(&lcur[b], 1);
        uint2 ed; ed.x = (u32)esrc[i]; ed.y = (u32)d;
        esorted[p] = ed;
    }
}

// One block per bucket: local count -> scan -> rowptr + norm -> CSR fill.
// (NO adjacency sort: round-8 measured it at +170 µs cost, ~0 prop gain.)
__global__ __launch_bounds__(256)
void bucket_fill(const uint2* __restrict__ esorted, const int* __restrict__ bbase,
                 int* __restrict__ rowptr, int* __restrict__ csr,
                 float* __restrict__ normv, int n, int e) {
    __shared__ int cnt[512], loc[512], tsum[256];
    const int b = blockIdx.x;
    const int ebeg = bbase[b], eend = bbase[b + 1];
    const int t = threadIdx.x;
    cnt[t] = 0; cnt[t + 256] = 0;
    __syncthreads();
    for (int i = ebeg + t; i < eend; i += 256)
        atomicAdd(&cnt[esorted[i].y & 511], 1);
    __syncthreads();
    int c0 = cnt[2 * t], c1 = cnt[2 * t + 1];
    tsum[t] = c0 + c1;
    __syncthreads();
    for (int off = 1; off < 256; off <<= 1) {
        int a = (t >= off) ? tsum[t - off] : 0;
        __syncthreads();
        tsum[t] += a;
        __syncthreads();
    }
    int excl = tsum[t] - (c0 + c1);
    loc[2 * t] = excl;
    loc[2 * t + 1] = excl + c0;
    __syncthreads();
    for (int j = t; j < 512; j += 256) {
        int node = (b << 9) + j;
        if (node < n) {
            rowptr[node] = ebeg + loc[j];
            int deg = cnt[j];
            normv[node] = (deg > 0) ? rsqrtf((float)deg) : 0.f;
        }
    }
    if (b == 0 && t == 0) rowptr[n] = e;
    __syncthreads();
    for (int j = t; j < 512; j += 256) cnt[j] = loc[j];
    __syncthreads();
    for (int i = ebeg + t; i < eend; i += 256) {
        uint2 ed = esorted[i];
        int slot = ebeg + atomicAdd(&cnt[ed.y & 511], 1);
        csr[slot] = (int)ed.x;
    }
}

// ---------------------------------------------------------------------------
// prop (feature-half phase): p[dst][foff:foff+64] for all dst.
// Two sequential phases shrink the gather footprint 51 MB -> 25.6 MB so the
// 16x row reuse hits cache instead of the fabric.
// Layout: wave = 1 node; lane = edge_slot(8) x feature_group(8); each lane
// loads uint4 = 8 bf16 -> 8 edges per wave-instruction, 16 per iteration.
// ---------------------------------------------------------------------------
__global__ __launch_bounds__(256)
void prop_half(const u16* __restrict__ hin, const float* __restrict__ norm,
               const int* __restrict__ rowptr, const int* __restrict__ csr,
               u16* __restrict__ pout, int n, int foff) {
    int wave = threadIdx.x >> 6;
    int lane = threadIdx.x & 63;
    int node = blockIdx.x * 4 + wave;
    if (node >= n) return;
    const int e8 = lane >> 3;                 // edge slot 0..7
    const int f  = foff + (lane & 7) * 8;     // feature offset (bf16 units)
    int s = rowptr[node], e = rowptr[node + 1];
    float a0 = 0, a1 = 0, a2 = 0, a3 = 0, a4 = 0, a5 = 0, a6 = 0, a7 = 0;
    int ib = s;
    if (ib + 16 <= e) {
        int sn0 = csr[ib + e8], sn1 = csr[ib + 8 + e8];
        while (true) {
            float nw0 = norm[sn0], nw1 = norm[sn1];
            uint4 v0 = *(const uint4*)(hin + (size_t)sn0 * 128 + f);
            uint4 v1 = *(const uint4*)(hin + (size_t)sn1 * 128 + f);
            int nb = ib + 16;
            bool more = (nb + 16 <= e);
            int t0 = 0, t1 = 0;
            if (more) { t0 = csr[nb + e8]; t1 = csr[nb + 8 + e8]; }
            a0 += bflo(v0.x) * nw0 + bflo(v1.x) * nw1;
            a1 += bfhi(v0.x) * nw0 + bfhi(v1.x) * nw1;
            a2 += bflo(v0.y) * nw0 + bflo(v1.y) * nw1;
            a3 += bfhi(v0.y) * nw0 + bfhi(v1.y) * nw1;
            a4 += bflo(v0.z) * nw0 + bflo(v1.z) * nw1;
            a5 += bfhi(v0.z) * nw0 + bfhi(v1.z) * nw1;
            a6 += bflo(v0.w) * nw0 + bflo(v1.w) * nw1;
            a7 += bfhi(v0.w) * nw0 + bfhi(v1.w) * nw1;
            ib = nb;
            if (!more) break;
            sn0 = t0; sn1 = t1;
        }
    }
    // remainder (< 16 edges), per-lane predicated
    if (ib + e8 < e) {
        int sn = csr[ib + e8];
        float nw = norm[sn];
        uint4 v = *(const uint4*)(hin + (size_t)sn * 128 + f);
        a0 += bflo(v.x) * nw; a1 += bfhi(v.x) * nw;
        a2 += bflo(v.y) * nw; a3 += bfhi(v.y) * nw;
        a4 += bflo(v.z) * nw; a5 += bfhi(v.z) * nw;
        a6 += bflo(v.w) * nw; a7 += bfhi(v.w) * nw;
    }
    if (ib + 8 + e8 < e) {
        int sn = csr[ib + 8 + e8];
        float nw = norm[sn];
        uint4 v = *(const uint4*)(hin + (size_t)sn * 128 + f);
        a0 += bflo(v.x) * nw; a1 += bfhi(v.x) * nw;
        a2 += bflo(v.y) * nw; a3 += bfhi(v.y) * nw;
        a4 += bflo(v.z) * nw; a5 += bfhi(v.z) * nw;
        a6 += bflo(v.w) * nw; a7 += bfhi(v.w) * nw;
    }
    // reduce over the 8 edge slots (stride-8 lanes): shfl_down 32, 16, 8
    a0 += __shfl_down(a0, 32, 64); a1 += __shfl_down(a1, 32, 64);
    a2 += __shfl_down(a2, 32, 64); a3 += __shfl_down(a3, 32, 64);
    a4 += __shfl_down(a4, 32, 64); a5 += __shfl_down(a5, 32, 64);
    a6 += __shfl_down(a6, 32, 64); a7 += __shfl_down(a7, 32, 64);
    a0 += __shfl_down(a0, 16, 64); a1 += __shfl_down(a1, 16, 64);
    a2 += __shfl_down(a2, 16, 64); a3 += __shfl_down(a3, 16, 64);
    a4 += __shfl_down(a4, 16, 64); a5 += __shfl_down(a5, 16, 64);
    a6 += __shfl_down(a6, 16, 64); a7 += __shfl_down(a7, 16, 64);
    a0 += __shfl_down(a0, 8, 64);  a1 += __shfl_down(a1, 8, 64);
    a2 += __shfl_down(a2, 8, 64);  a3 += __shfl_down(a3, 8, 64);
    a4 += __shfl_down(a4, 8, 64);  a5 += __shfl_down(a5, 8, 64);
    a6 += __shfl_down(a6, 8, 64);  a7 += __shfl_down(a7, 8, 64);
    if (e8 == 0) {
        float nd = norm[node];
        uint4 o;
        o.x = pack2(a0 * nd, a1 * nd);
        o.y = pack2(a2 * nd, a3 * nd);
        o.z = pack2(a4 * nd, a5 * nd);
        o.w = pack2(a6 * nd, a7 * nd);
        *(uint4*)(pout + (size_t)node * 128 + f) = o;
    }
}

// ---------------------------------------------------------------------------
// MFMA GEMM + fused BN stats (direct global->LDS staging; register-prefetch
// variant spilled to scratch — do not reintroduce)
// ---------------------------------------------------------------------------
template <int DOUT>
__global__ __launch_bounds__(256)
void gemm_mfma(const u16* __restrict__ A0, const u16* __restrict__ A1,
               const u16* __restrict__ A2, const u16* __restrict__ whi,
               const u16* __restrict__ wlo, u16* __restrict__ outp,
               float* __restrict__ gstats, int n) {
    constexpr int TJ = DOUT / 64;
    constexpr int BELEMS = DOUT * 64;
    __shared__ u16 As[128 * 64];
    __shared__ u16 Bh[BELEMS];
    __shared__ u16 Bl[BELEMS];
    __shared__ float col_s[DOUT];
    __shared__ float col_q[DOUT];

    const int tid  = threadIdx.x;
    const int wave = tid >> 6;
    const int lane = tid & 63;
    const int wrow = wave >> 1;
    const int wcol = wave & 1;
    const int row0 = blockIdx.x * 128;
    const int m    = lane & 31;
    const int half = lane >> 5;

    const u16* mats[3] = {A0, A1, A2};

    floatx16 acc[2][TJ];
#pragma unroll
    for (int ti = 0; ti < 2; ++ti)
#pragma unroll
        for (int tj = 0; tj < TJ; ++tj)
#pragma unroll
            for (int r = 0; r < 16; ++r) acc[ti][tj][r] = 0.f;

    for (int c = 0; c < 6; ++c) {
        const u16* M = mats[c >> 1];
        const int kloc = (c & 1) * 64;
#pragma unroll
        for (int it = 0; it < 4; ++it) {
            int rib  = wave * 32 + it * 8 + (lane >> 3);
            int grow = row0 + rib;
            if (grow >= n) grow = n - 1;
            uint4 v = *(const uint4*)(M + (size_t)grow * 128 + kloc + (lane & 7) * 8);
            int cc = (lane & 7) ^ (rib & 7);
            *(uint4*)&As[rib * 64 + cc * 8] = v;
        }
        {
            const int cbase = c * BELEMS;
#pragma unroll
            for (int j = 0; j < BELEMS / 2048; ++j) {
                int idx  = tid + j * 256;
                int nrow = idx >> 3, seg = idx & 7;
                int dcc  = seg ^ (nrow & 7);
                *(uint4*)&Bh[nrow * 64 + dcc * 8] =
                    *(const uint4*)(whi + cbase + idx * 8);
                *(uint4*)&Bl[nrow * 64 + dcc * 8] =
                    *(const uint4*)(wlo + cbase + idx * 8);
            }
        }
        __syncthreads();
#pragma unroll
        for (int s = 0; s < 4; ++s) {
            const int cc = s * 2 + half;
            short8 a[2], bhf[TJ], blf[TJ];
#pragma unroll
            for (int ti = 0; ti < 2; ++ti) {
                int r = wrow * 64 + ti * 32 + m;
                a[ti] = *(const short8*)&As[r * 64 + ((cc ^ (r & 7)) * 8)];
            }
#pragma unroll
            for (int tj = 0; tj < TJ; ++tj) {
                int rr = wcol * TJ * 32 + tj * 32 + m;
                int off = rr * 64 + ((cc ^ (rr & 7)) * 8);
                bhf[tj] = *(const short8*)&Bh[off];
                blf[tj] = *(const short8*)&Bl[off];
            }
#pragma unroll
            for (int ti = 0; ti < 2; ++ti)
#pragma unroll
                for (int tj = 0; tj < TJ; ++tj) {
                    acc[ti][tj] = __builtin_amdgcn_mfma_f32_32x32x16_bf16(
                        a[ti], bhf[tj], acc[ti][tj], 0, 0, 0);
                    acc[ti][tj] = __builtin_amdgcn_mfma_f32_32x32x16_bf16(
                        a[ti], blf[tj], acc[ti][tj], 0, 0, 0);
                }
        }
        __syncthreads();
    }

    if (tid < DOUT) { col_s[tid] = 0.f; col_q[tid] = 0.f; }
    __syncthreads();
#pragma unroll
    for (int tj = 0; tj < TJ; ++tj) {
        int gcol = (wcol * TJ + tj) * 32 + m;
        float s = 0.f, qq = 0.f;
#pragma unroll
        for (int ti = 0; ti < 2; ++ti)
#pragma unroll
            for (int r = 0; r < 16; ++r) {
                int grow = row0 + wrow * 64 + ti * 32 + (r & 3) + 8 * (r >> 2) + 4 * half;
                if (grow < n) {
                    float v = acc[ti][tj][r];
                    s += v; qq += v * v;
                    outp[(size_t)grow * DOUT + gcol] = (u16)f2bf(v);
                }
            }
        atomicAdd(&col_s[gcol], s);
        atomicAdd(&col_q[gcol], qq);
    }
    __syncthreads();
    if (tid < DOUT) {
        atomicAdd(&gstats[tid], col_s[tid]);
        atomicAdd(&gstats[DOUT + tid], col_q[tid]);
    }
}

// ---------------------------------------------------------------------------
// BN apply with inline finalize (scale/shift from raw sums per block)
// ---------------------------------------------------------------------------
template <int DOUT, bool SKIP>
__global__ __launch_bounds__(256)
void bn_apply(u16* __restrict__ h, const float* __restrict__ stats,
              const float* __restrict__ gamma, const float* __restrict__ beta,
              const u16* __restrict__ skip, int total4, float inv_n) {
    constexpr int C4 = DOUT / 4;
    __shared__ float sh_scale[DOUT], sh_shift[DOUT];
    if (threadIdx.x < DOUT) {
        int t = threadIdx.x;
        float mm = stats[t] * inv_n;
        float var = stats[DOUT + t] * inv_n - mm * mm;
        float sc = rsqrtf(var + BN_EPS) * gamma[t];
        sh_scale[t] = sc;
        sh_shift[t] = beta[t] - mm * sc;
    }
    __syncthreads();
    for (int idx = blockIdx.x * 256 + threadIdx.x; idx < total4; idx += gridDim.x * 256) {
        int c4 = (idx % C4) * 4;
        uint2 u = ((const uint2*)h)[idx];
        float v0 = bflo(u.x), v1 = bfhi(u.x), v2 = bflo(u.y), v3 = bfhi(u.y);
        v0 = fmaxf(fmaf(v0, sh_scale[c4 + 0], sh_shift[c4 + 0]), 0.f);
        v1 = fmaxf(fmaf(v1, sh_scale[c4 + 1], sh_shift[c4 + 1]), 0.f);
        v2 = fmaxf(fmaf(v2, sh_scale[c4 + 2], sh_shift[c4 + 2]), 0.f);
        v3 = fmaxf(fmaf(v3, sh_scale[c4 + 3], sh_shift[c4 + 3]), 0.f);
        if (SKIP) {
            uint2 sk = ((const uint2*)skip)[idx];
            v0 += bflo(sk.x); v1 += bfhi(sk.x); v2 += bflo(sk.y); v3 += bfhi(sk.y);
        }
        uint2 o; o.x = pack2(v0, v1); o.y = pack2(v2, v3);
        ((uint2*)h)[idx] = o;
    }
}

// ---------------------------------------------------------------------------
// graph boundaries from sorted segment_ids
// ---------------------------------------------------------------------------
__global__ void gstart_kernel(const int* __restrict__ seg, int* __restrict__ gstart,
                              int n, int g_count) {
    int i = blockIdx.x * 256 + threadIdx.x;
    if (i >= n) return;
    int cur = seg[i];
    if (i == 0) {
        for (int g = 0; g <= cur; ++g) gstart[g] = 0;
    } else {
        int prev = seg[i - 1];
        for (int g = prev + 1; g <= cur; ++g) gstart[g] = i;
    }
    if (i == n - 1) {
        for (int g = cur + 1; g <= g_count; ++g) gstart[g] = n;
    }
}

// ---------------------------------------------------------------------------
// pooling over RAW layer-5 output with fused BN affine + ReLU
// ---------------------------------------------------------------------------
__global__ __launch_bounds__(256)
void pool_kernel(const u16* __restrict__ hraw, const float* __restrict__ stats,
                 const float* __restrict__ gamma, const float* __restrict__ beta,
                 const int* __restrict__ gstart, float* __restrict__ pooled,
                 int g_count, float inv_n) {
    int wave = threadIdx.x >> 6;
    int lane = threadIdx.x & 63;
    int g = blockIdx.x * 4 + wave;
    if (g >= g_count) return;
    float mmean = stats[lane] * inv_n;
    float var = stats[64 + lane] * inv_n - mmean * mmean;
    float sc = rsqrtf(var + BN_EPS) * gamma[lane];
    float sh = beta[lane] - mmean * sc;
    int s = gstart[g], e = gstart[g + 1];
    float mx = -INFINITY, mn = INFINITY, sm = 0.f, sq = 0.f;
    for (int nidx = s; nidx < e; ++nidx) {
        float v = fmaxf(fmaf(bf1(hraw[(size_t)nidx * 64 + lane]), sc, sh), 0.f);
        mx = fmaxf(mx, v);
        mn = fminf(mn, v);
        sm += v;
        sq += v * v;
    }
    float cnt = (float)(e - s);
    float mean = sm / fmaxf(cnt, 1.f);
    float var2 = (sq - cnt * mean * mean) / fmaxf(cnt - 1.f, 1.f);
    float sd = sqrtf(fmaxf(var2, 0.f));
    size_t base = (size_t)g * 256;
    pooled[base + 0 * 64 + lane] = mx;
    pooled[base + 1 * 64 + lane] = mn;
    pooled[base + 2 * 64 + lane] = mean;
    pooled[base + 3 * 64 + lane] = sd;
}

__global__ void agg_stats(const float* __restrict__ pooled, float* __restrict__ aggstat,
                          int g_count) {
    int ch = blockIdx.x;
    int total = g_count * 64;
    float s = 0.f, q = 0.f;
    for (int i = threadIdx.x; i < total; i += 256) {
        int g = i >> 6, f = i & 63;
        float v = pooled[(size_t)g * 256 + ch * 64 + f];
        s += v; q += v * v;
    }
    __shared__ float ls[256], lq[256];
    ls[threadIdx.x] = s; lq[threadIdx.x] = q;
    __syncthreads();
    for (int off = 128; off > 0; off >>= 1) {
        if (threadIdx.x < off) {
            ls[threadIdx.x] += ls[threadIdx.x + off];
            lq[threadIdx.x] += lq[threadIdx.x + off];
        }
        __syncthreads();
    }
    if (threadIdx.x == 0) {
        float inv = 1.f / (float)total;
        float m = ls[0] * inv;
        aggstat[ch * 2 + 0] = m;
        aggstat[ch * 2 + 1] = lq[0] * inv - m * m;
    }
}

__global__ __launch_bounds__(256)
void final_kernel(const float* __restrict__ pooled, const float* __restrict__ aggstat,
                  const float* __restrict__ agg_gamma, const float* __restrict__ agg_beta,
                  const float* __restrict__ aggW, const float* __restrict__ aggb,
                  const float* __restrict__ outW, const float* __restrict__ outb,
                  float* __restrict__ out, int g_count) {
    __shared__ float sflat[4][256];
    int wave = threadIdx.x >> 6;
    int lane = threadIdx.x & 63;
    int g = blockIdx.x * 4 + wave;
    if (g < g_count) {
#pragma unroll
        for (int c = 0; c < 4; ++c) {
            float v = pooled[(size_t)g * 256 + c * 64 + lane];
            float m = aggstat[c * 2], var = aggstat[c * 2 + 1];
            v = (v - m) * rsqrtf(var + BN_EPS) * agg_gamma[c] + agg_beta[c];
            sflat[wave][c * 64 + lane] = v;
        }
    }
    __syncthreads();
    if (g < g_count) {
        float acc = aggb[lane];
        const float* wrow = aggW + lane * 256;
#pragma unroll 8
        for (int i = 0; i < 256; ++i)
            acc = fmaf(sflat[wave][i], wrow[i], acc);
        float t = acc * outW[lane];
        for (int off = 32; off > 0; off >>= 1) t += __shfl_down(t, off, 64);
        if (lane == 0) out[g] = t + outb[0];
    }
}

// ---------------------------------------------------------------------------
// host launcher
// ---------------------------------------------------------------------------
extern "C" void kernel_launch(void* const* d_in, const int* in_sizes, int n_in,
                              void* d_out, int out_size, void* d_ws, size_t ws_size,
                              hipStream_t stream) {
    const int N = N_NODES, E = N_EDGES, G = N_GRAPHS;

    const float* x           = (const float*)d_in[0];
    const int*   ei          = (const int*)d_in[1];
    const int*   seg         = (const int*)d_in[2];
    const float* conv_W      = (const float*)d_in[3];
    const float* conv_W_last = (const float*)d_in[4];
    const float* bn_g        = (const float*)d_in[5];
    const float* bn_b        = (const float*)d_in[6];
    const float* bn_gl       = (const float*)d_in[7];
    const float* bn_bl       = (const float*)d_in[8];
    const float* agg_g       = (const float*)d_in[9];
    const float* agg_bt      = (const float*)d_in[10];
    const float* aggW        = (const float*)d_in[11];
    const float* aggb        = (const float*)d_in[12];
    const float* outW        = (const float*)d_in[13];
    const float* outb        = (const float*)d_in[14];
    float* out = (float*)d_out;

    const int* esrc = ei;
    const int* edst = ei + E;

    size_t off = 0;
    auto alloc = [&](size_t bytes) -> void* {
        void* p = (char*)d_ws + off;
        off += (bytes + 255) & ~(size_t)255;
        return p;
    };
    float* normv  = (float*)alloc((size_t)N * 4);
    int*   rowptr = (int*)alloc((size_t)(N + 1) * 4);
    int*   csr    = (int*)alloc((size_t)E * 4);
    int*   bcnt   = (int*)alloc((NB + 1) * 4);
    int*   bbase  = (int*)alloc((NB + 1) * 4);
    int*   bcur   = (int*)alloc((NB + 1) * 4);
    int*   gstart = (int*)alloc((size_t)(G + 1) * 4);
    float* statsA = (float*)alloc(6 * 256 * 4);
    float* aggstat= (float*)alloc(8 * 4);
    float* pooled = (float*)alloc((size_t)G * 256 * 4);
    const size_t WPACK = 5 * 384 * 128 + 384 * 64;
    u16*   whip   = (u16*)alloc(WPACK * 2);
    u16*   wlop   = (u16*)alloc(WPACK * 2);
    u16*   ring0  = (u16*)alloc((size_t)N * 128 * 2);
    u16*   ring1  = (u16*)alloc((size_t)N * 128 * 2);
    u16*   ring2  = (u16*)alloc((size_t)N * 128 * 2);
    u16*   p1     = (u16*)alloc((size_t)N * 128 * 2);
    u16*   p2     = (u16*)alloc((size_t)N * 128 * 2);
    u16*   ring[3] = {ring0, ring1, ring2};
    uint2* esorted = (uint2*)p2;   // alias: dead before first prop writes p2

    // ---- CSR build (multisplit) + norm ----
    hipMemsetAsync(bcnt, 0, (NB + 1) * 4, stream);
    hipMemsetAsync(statsA, 0, 6 * 256 * 4, stream);
    const int nchunk = (E + CHUNK - 1) / CHUNK;
    bucket_hist<<<nchunk, 256, 0, stream>>>(edst, bcnt, E);
    bucket_scan<<<1, 512, 0, stream>>>(bcnt, bbase, bcur);
    bucket_scatter<<<nchunk, 256, 0, stream>>>(esrc, edst, bcur, esorted, E);
    bucket_fill<<<NB, 256, 0, stream>>>(esorted, bbase, rowptr, csr, normv, N, E);

    // ---- x -> bf16 (into ring2; dead before layer 2 writes it) ----
    x2bf_kernel<<<2048, 256, 0, stream>>>(x, ring2, N * 128 / 4);

    // ---- W pack (single launch) ----
    wpack_all<<<(5 * 384 * 128 + 384 * 64 + 255) / 256, 256, 0, stream>>>(
        conv_W, conv_W_last, whip, wlop);

    // ---- graph boundaries ----
    gstart_kernel<<<(N + 255) / 256, 256, 0, stream>>>(seg, gstart, N, G);

    // ---- layers ----
    const u16* h_in = ring2;
    const int gemm_grid = (N + 127) / 128;
    const int prop_grid = (N + 3) / 4;
    const float inv_n = 1.f / (float)N;
    for (int l = 0; l < 6; ++l) {
        const int dout = (l < 5) ? 128 : 64;
        const u16* whi = whip + (size_t)((l < 5) ? l * 384 * 128 : 5 * 384 * 128);
        const u16* wlo = wlop + (size_t)((l < 5) ? l * 384 * 128 : 5 * 384 * 128);
        const float* gamma = (l < 5) ? (bn_g + l * 128) : bn_gl;
        const float* beta  = (l < 5) ? (bn_b + l * 128) : bn_bl;
        float* stats = statsA + l * 256;
        u16* outbuf = ring[l % 3];

        // two feature-half phases per prop (sequential on the stream so each
        // phase's 25.6 MB footprint is cache-resident)
        prop_half<<<prop_grid, 256, 0, stream>>>(h_in, normv, rowptr, csr, p1, N, 0);
        prop_half<<<prop_grid, 256, 0, stream>>>(h_in, normv, rowptr, csr, p1, N, 64);
        prop_half<<<prop_grid, 256, 0, stream>>>(p1, normv, rowptr, csr, p2, N, 0);
        prop_half<<<prop_grid, 256, 0, stream>>>(p1, normv, rowptr, csr, p2, N, 64);

        if (dout == 128)
            gemm_mfma<128><<<gemm_grid, 256, 0, stream>>>(h_in, p1, p2, whi, wlo, outbuf,
                                                          stats, N);
        else
            gemm_mfma<64><<<gemm_grid, 256, 0, stream>>>(h_in, p1, p2, whi, wlo, outbuf,
                                                         stats, N);

        if (l < 5) {
            int total4 = N * dout / 4;
            bool has_skip = (l >= 2);
            const u16* skipb = has_skip ? ring[(l - 2) % 3] : nullptr;
            if (has_skip)
                bn_apply<128, true><<<8192, 256, 0, stream>>>(outbuf, stats, gamma, beta,
                                                              skipb, total4, inv_n);
            else
                bn_apply<128, false><<<8192, 256, 0, stream>>>(outbuf, stats, gamma, beta,
                                                               nullptr, total4, inv_n);
        }
        h_in = outbuf;
    }

    // ---- pooling (fused layer-5 BN affine) + head ----
    pool_kernel<<<(G + 3) / 4, 256, 0, stream>>>(ring[5 % 3], statsA + 5 * 256,
                                                 bn_gl, bn_bl, gstart, pooled, G, inv_n);
    agg_stats<<<4, 256, 0, stream>>>(pooled, aggstat, G);
    final_kernel<<<(G + 3) / 4, 256, 0, stream>>>(pooled, aggstat, agg_g, agg_bt,
                                                  aggW, aggb, outW, outb, out, G);
}

// Round 10
// 2609.057 us; speedup vs baseline: 1.1936x; 1.1936x over previous
//
#include <hip/hip_runtime.h>
#include <cstddef>
#include <cstdint>

#define N_NODES  200000
#define N_EDGES  3200000
#define N_GRAPHS 2000
#define BN_EPS   1e-5f
#define NB       391          // ceil(N / 512) buckets
#define BSH      9            // bucket = dst >> 9 (512 nodes per bucket)
#define CHUNK    16384        // edges per block in hist/scatter

typedef unsigned int   u32;
typedef unsigned short u16;

using short8   = __attribute__((ext_vector_type(8))) short;
using floatx16 = __attribute__((ext_vector_type(16))) float;

// ---------------------------------------------------------------------------
// bf16 helpers (raw-bit, RNE pack)
// ---------------------------------------------------------------------------
__device__ __forceinline__ float bflo(u32 v) { union {u32 i; float f;} c; c.i = v << 16; return c.f; }
__device__ __forceinline__ float bfhi(u32 v) { union {u32 i; float f;} c; c.i = v & 0xffff0000u; return c.f; }
__device__ __forceinline__ float bf1(u16 v)  { union {u32 i; float f;} c; c.i = ((u32)v) << 16; return c.f; }
__device__ __forceinline__ u32 f2bf(float f) {
    union {float f; u32 i;} c; c.f = f;
    return (c.i + 0x7fffu + ((c.i >> 16) & 1u)) >> 16;
}
__device__ __forceinline__ u32 pack2(float a, float b) { return f2bf(a) | (f2bf(b) << 16); }

// ---------------------------------------------------------------------------
// x (fp32) -> bf16
// ---------------------------------------------------------------------------
__global__ void x2bf_kernel(const float* __restrict__ x, u16* __restrict__ xb, int total4) {
    for (int i = blockIdx.x * 256 + threadIdx.x; i < total4; i += gridDim.x * 256) {
        float4 v = ((const float4*)x)[i];
        uint2 o; o.x = pack2(v.x, v.y); o.y = pack2(v.z, v.w);
        ((uint2*)xb)[i] = o;
    }
}

// ---------------------------------------------------------------------------
// W pack (all 6 layers in one launch): fp32 -> transposed K-chunked hi/lo bf16
// ---------------------------------------------------------------------------
__global__ void wpack_all(const float* __restrict__ convW, const float* __restrict__ convWlast,
                          u16* __restrict__ whi, u16* __restrict__ wlo) {
    const int PER = 384 * 128;
    int tid = blockIdx.x * 256 + threadIdx.x;
    float w;
    int dst;
    if (tid < 5 * PER) {
        int l = tid / PER, r = tid % PER;
        int k = r / 128, nn = r % 128;
        w = convW[tid];
        dst = l * PER + (k >> 6) * 128 * 64 + nn * 64 + (k & 63);
    } else {
        int r = tid - 5 * PER;
        if (r >= 384 * 64) return;
        int k = r / 64, nn = r % 64;
        w = convWlast[r];
        dst = 5 * PER + (k >> 6) * 64 * 64 + nn * 64 + (k & 63);
    }
    u16 hi = (u16)f2bf(w);
    float rem = w - bf1(hi);
    whi[dst] = hi;
    wlo[dst] = (u16)f2bf(rem);
}

// ---------------------------------------------------------------------------
// CSR build via 391-bucket multisplit (bucket = dst >> 9)
// ---------------------------------------------------------------------------
__global__ __launch_bounds__(256)
void bucket_hist(const int* __restrict__ edst, int* __restrict__ bcnt, int e) {
    __shared__ int h[NB];
    for (int t = threadIdx.x; t < NB; t += 256) h[t] = 0;
    __syncthreads();
    int base = blockIdx.x * CHUNK;
    int end  = min(base + CHUNK, e);
    for (int i = base + threadIdx.x; i < end; i += 256)
        atomicAdd(&h[edst[i] >> BSH], 1);
    __syncthreads();
    for (int t = threadIdx.x; t < NB; t += 256)
        if (h[t]) atomicAdd(&bcnt[t], h[t]);
}

__global__ void bucket_scan(const int* __restrict__ bcnt, int* __restrict__ bbase,
                            int* __restrict__ bcur) {
    __shared__ int ls[512];
    int t = threadIdx.x;
    int v = (t < NB) ? bcnt[t] : 0;
    ls[t] = v;
    __syncthreads();
    for (int off = 1; off < 512; off <<= 1) {
        int a = (t >= off) ? ls[t - off] : 0;
        __syncthreads();
        ls[t] += a;
        __syncthreads();
    }
    if (t <= NB) {
        int excl = ls[t] - v;
        bbase[t] = excl;
        if (t < NB) bcur[t] = excl;
    }
}

__global__ __launch_bounds__(256)
void bucket_scatter(const int* __restrict__ esrc, const int* __restrict__ edst,
                    int* __restrict__ bcur, uint2* __restrict__ esorted, int e) {
    __shared__ int h[NB], lbase[NB], lcur[NB];
    for (int t = threadIdx.x; t < NB; t += 256) { h[t] = 0; lcur[t] = 0; }
    __syncthreads();
    int base = blockIdx.x * CHUNK;
    int end  = min(base + CHUNK, e);
    for (int i = base + threadIdx.x; i < end; i += 256)
        atomicAdd(&h[edst[i] >> BSH], 1);
    __syncthreads();
    for (int t = threadIdx.x; t < NB; t += 256)
        lbase[t] = h[t] ? atomicAdd(&bcur[t], h[t]) : 0;
    __syncthreads();
    for (int i = base + threadIdx.x; i < end; i += 256) {
        int d = edst[i];
        int b = d >> BSH;
        int p = lbase[b] + atomicAdd(&lcur[b], 1);
        uint2 ed; ed.x = (u32)esrc[i]; ed.y = (u32)d;
        esorted[p] = ed;
    }
}

// One block per bucket: local count -> scan -> rowptr + norm -> CSR fill.
// (No adjacency sort: round-8 measured +170 µs cost, ~0 prop gain.)
__global__ __launch_bounds__(256)
void bucket_fill(const uint2* __restrict__ esorted, const int* __restrict__ bbase,
                 int* __restrict__ rowptr, int* __restrict__ csr,
                 float* __restrict__ normv, int n, int e) {
    __shared__ int cnt[512], loc[512], tsum[256];
    const int b = blockIdx.x;
    const int ebeg = bbase[b], eend = bbase[b + 1];
    const int t = threadIdx.x;
    cnt[t] = 0; cnt[t + 256] = 0;
    __syncthreads();
    for (int i = ebeg + t; i < eend; i += 256)
        atomicAdd(&cnt[esorted[i].y & 511], 1);
    __syncthreads();
    int c0 = cnt[2 * t], c1 = cnt[2 * t + 1];
    tsum[t] = c0 + c1;
    __syncthreads();
    for (int off = 1; off < 256; off <<= 1) {
        int a = (t >= off) ? tsum[t - off] : 0;
        __syncthreads();
        tsum[t] += a;
        __syncthreads();
    }
    int excl = tsum[t] - (c0 + c1);
    loc[2 * t] = excl;
    loc[2 * t + 1] = excl + c0;
    __syncthreads();
    for (int j = t; j < 512; j += 256) {
        int node = (b << 9) + j;
        if (node < n) {
            rowptr[node] = ebeg + loc[j];
            int deg = cnt[j];
            normv[node] = (deg > 0) ? rsqrtf((float)deg) : 0.f;
        }
    }
    if (b == 0 && t == 0) rowptr[n] = e;
    __syncthreads();
    for (int j = t; j < 512; j += 256) cnt[j] = loc[j];
    __syncthreads();
    for (int i = ebeg + t; i < eend; i += 256) {
        uint2 ed = esorted[i];
        int slot = ebeg + atomicAdd(&cnt[ed.y & 511], 1);
        csr[slot] = (int)ed.x;
    }
}

// ---------------------------------------------------------------------------
// prop (round-7 form — measured floor 129.8 µs; ILP/order/footprint variants
// all neutral or worse): quarter-wave gather, 16 edges/iter, index prefetch.
// ---------------------------------------------------------------------------
__global__ __launch_bounds__(256)
void prop_kernel(const u16* __restrict__ hin, const float* __restrict__ norm,
                 const int* __restrict__ rowptr, const int* __restrict__ csr,
                 u16* __restrict__ pout, int n) {
    int wave = threadIdx.x >> 6;
    int lane = threadIdx.x & 63;
    int node = blockIdx.x * 4 + wave;
    if (node >= n) return;
    const int q = lane >> 4;
    const int f = (lane & 15) * 8;
    int s = rowptr[node], e = rowptr[node + 1];
    float a0 = 0, a1 = 0, a2 = 0, a3 = 0, a4 = 0, a5 = 0, a6 = 0, a7 = 0;
    int i = s + q;
    if (i + 12 < e) {
        int sn0 = csr[i], sn1 = csr[i + 4], sn2 = csr[i + 8], sn3 = csr[i + 12];
        while (true) {
            float nw0 = norm[sn0], nw1 = norm[sn1], nw2 = norm[sn2], nw3 = norm[sn3];
            uint4 v0 = *(const uint4*)(hin + (size_t)sn0 * 128 + f);
            uint4 v1 = *(const uint4*)(hin + (size_t)sn1 * 128 + f);
            uint4 v2 = *(const uint4*)(hin + (size_t)sn2 * 128 + f);
            uint4 v3 = *(const uint4*)(hin + (size_t)sn3 * 128 + f);
            int ni = i + 16;
            bool more = (ni + 12 < e);
            int t0 = 0, t1 = 0, t2 = 0, t3 = 0;
            if (more) {
                t0 = csr[ni]; t1 = csr[ni + 4]; t2 = csr[ni + 8]; t3 = csr[ni + 12];
            }
            a0 += bflo(v0.x) * nw0 + bflo(v1.x) * nw1 + bflo(v2.x) * nw2 + bflo(v3.x) * nw3;
            a1 += bfhi(v0.x) * nw0 + bfhi(v1.x) * nw1 + bfhi(v2.x) * nw2 + bfhi(v3.x) * nw3;
            a2 += bflo(v0.y) * nw0 + bflo(v1.y) * nw1 + bflo(v2.y) * nw2 + bflo(v3.y) * nw3;
            a3 += bfhi(v0.y) * nw0 + bfhi(v1.y) * nw1 + bfhi(v2.y) * nw2 + bfhi(v3.y) * nw3;
            a4 += bflo(v0.z) * nw0 + bflo(v1.z) * nw1 + bflo(v2.z) * nw2 + bflo(v3.z) * nw3;
            a5 += bfhi(v0.z) * nw0 + bfhi(v1.z) * nw1 + bfhi(v2.z) * nw2 + bfhi(v3.z) * nw3;
            a6 += bflo(v0.w) * nw0 + bflo(v1.w) * nw1 + bflo(v2.w) * nw2 + bflo(v3.w) * nw3;
            a7 += bfhi(v0.w) * nw0 + bfhi(v1.w) * nw1 + bfhi(v2.w) * nw2 + bfhi(v3.w) * nw3;
            i = ni;
            if (!more) break;
            sn0 = t0; sn1 = t1; sn2 = t2; sn3 = t3;
        }
    }
    for (; i < e; i += 4) {
        int sn0 = csr[i];
        float nw0 = norm[sn0];
        uint4 v0 = *(const uint4*)(hin + (size_t)sn0 * 128 + f);
        a0 += bflo(v0.x) * nw0; a1 += bfhi(v0.x) * nw0;
        a2 += bflo(v0.y) * nw0; a3 += bfhi(v0.y) * nw0;
        a4 += bflo(v0.z) * nw0; a5 += bfhi(v0.z) * nw0;
        a6 += bflo(v0.w) * nw0; a7 += bfhi(v0.w) * nw0;
    }
    a0 += __shfl_down(a0, 32, 64); a1 += __shfl_down(a1, 32, 64);
    a2 += __shfl_down(a2, 32, 64); a3 += __shfl_down(a3, 32, 64);
    a4 += __shfl_down(a4, 32, 64); a5 += __shfl_down(a5, 32, 64);
    a6 += __shfl_down(a6, 32, 64); a7 += __shfl_down(a7, 32, 64);
    a0 += __shfl_down(a0, 16, 64); a1 += __shfl_down(a1, 16, 64);
    a2 += __shfl_down(a2, 16, 64); a3 += __shfl_down(a3, 16, 64);
    a4 += __shfl_down(a4, 16, 64); a5 += __shfl_down(a5, 16, 64);
    a6 += __shfl_down(a6, 16, 64); a7 += __shfl_down(a7, 16, 64);
    if (q == 0) {
        float nd = norm[node];
        uint4 o;
        o.x = pack2(a0 * nd, a1 * nd);
        o.y = pack2(a2 * nd, a3 * nd);
        o.z = pack2(a4 * nd, a5 * nd);
        o.w = pack2(a6 * nd, a7 * nd);
        *(uint4*)(pout + (size_t)node * 128 + f) = o;
    }
}

// ---------------------------------------------------------------------------
// MFMA GEMM + fused BN stats (direct global->LDS staging; register-prefetch
// variant spilled to scratch — do not reintroduce)
// ---------------------------------------------------------------------------
template <int DOUT>
__global__ __launch_bounds__(256)
void gemm_mfma(const u16* __restrict__ A0, const u16* __restrict__ A1,
               const u16* __restrict__ A2, const u16* __restrict__ whi,
               const u16* __restrict__ wlo, u16* __restrict__ outp,
               float* __restrict__ gstats, int n) {
    constexpr int TJ = DOUT / 64;
    constexpr int BELEMS = DOUT * 64;
    __shared__ u16 As[128 * 64];
    __shared__ u16 Bh[BELEMS];
    __shared__ u16 Bl[BELEMS];
    __shared__ float col_s[DOUT];
    __shared__ float col_q[DOUT];

    const int tid  = threadIdx.x;
    const int wave = tid >> 6;
    const int lane = tid & 63;
    const int wrow = wave >> 1;
    const int wcol = wave & 1;
    const int row0 = blockIdx.x * 128;
    const int m    = lane & 31;
    const int half = lane >> 5;

    const u16* mats[3] = {A0, A1, A2};

    floatx16 acc[2][TJ];
#pragma unroll
    for (int ti = 0; ti < 2; ++ti)
#pragma unroll
        for (int tj = 0; tj < TJ; ++tj)
#pragma unroll
            for (int r = 0; r < 16; ++r) acc[ti][tj][r] = 0.f;

    for (int c = 0; c < 6; ++c) {
        const u16* M = mats[c >> 1];
        const int kloc = (c & 1) * 64;
#pragma unroll
        for (int it = 0; it < 4; ++it) {
            int rib  = wave * 32 + it * 8 + (lane >> 3);
            int grow = row0 + rib;
            if (grow >= n) grow = n - 1;
            uint4 v = *(const uint4*)(M + (size_t)grow * 128 + kloc + (lane & 7) * 8);
            int cc = (lane & 7) ^ (rib & 7);
            *(uint4*)&As[rib * 64 + cc * 8] = v;
        }
        {
            const int cbase = c * BELEMS;
#pragma unroll
            for (int j = 0; j < BELEMS / 2048; ++j) {
                int idx  = tid + j * 256;
                int nrow = idx >> 3, seg = idx & 7;
                int dcc  = seg ^ (nrow & 7);
                *(uint4*)&Bh[nrow * 64 + dcc * 8] =
                    *(const uint4*)(whi + cbase + idx * 8);
                *(uint4*)&Bl[nrow * 64 + dcc * 8] =
                    *(const uint4*)(wlo + cbase + idx * 8);
            }
        }
        __syncthreads();
#pragma unroll
        for (int s = 0; s < 4; ++s) {
            const int cc = s * 2 + half;
            short8 a[2], bhf[TJ], blf[TJ];
#pragma unroll
            for (int ti = 0; ti < 2; ++ti) {
                int r = wrow * 64 + ti * 32 + m;
                a[ti] = *(const short8*)&As[r * 64 + ((cc ^ (r & 7)) * 8)];
            }
#pragma unroll
            for (int tj = 0; tj < TJ; ++tj) {
                int rr = wcol * TJ * 32 + tj * 32 + m;
                int off = rr * 64 + ((cc ^ (rr & 7)) * 8);
                bhf[tj] = *(const short8*)&Bh[off];
                blf[tj] = *(const short8*)&Bl[off];
            }
#pragma unroll
            for (int ti = 0; ti < 2; ++ti)
#pragma unroll
                for (int tj = 0; tj < TJ; ++tj) {
                    acc[ti][tj] = __builtin_amdgcn_mfma_f32_32x32x16_bf16(
                        a[ti], bhf[tj], acc[ti][tj], 0, 0, 0);
                    acc[ti][tj] = __builtin_amdgcn_mfma_f32_32x32x16_bf16(
                        a[ti], blf[tj], acc[ti][tj], 0, 0, 0);
                }
        }
        __syncthreads();
    }

    if (tid < DOUT) { col_s[tid] = 0.f; col_q[tid] = 0.f; }
    __syncthreads();
#pragma unroll
    for (int tj = 0; tj < TJ; ++tj) {
        int gcol = (wcol * TJ + tj) * 32 + m;
        float s = 0.f, qq = 0.f;
#pragma unroll
        for (int ti = 0; ti < 2; ++ti)
#pragma unroll
            for (int r = 0; r < 16; ++r) {
                int grow = row0 + wrow * 64 + ti * 32 + (r & 3) + 8 * (r >> 2) + 4 * half;
                if (grow < n) {
                    float v = acc[ti][tj][r];
                    s += v; qq += v * v;
                    outp[(size_t)grow * DOUT + gcol] = (u16)f2bf(v);
                }
            }
        atomicAdd(&col_s[gcol], s);
        atomicAdd(&col_q[gcol], qq);
    }
    __syncthreads();
    if (tid < DOUT) {
        atomicAdd(&gstats[tid], col_s[tid]);
        atomicAdd(&gstats[DOUT + tid], col_q[tid]);
    }
}

// ---------------------------------------------------------------------------
// BN apply with inline finalize (scale/shift from raw sums per block)
// ---------------------------------------------------------------------------
template <int DOUT, bool SKIP>
__global__ __launch_bounds__(256)
void bn_apply(u16* __restrict__ h, const float* __restrict__ stats,
              const float* __restrict__ gamma, const float* __restrict__ beta,
              const u16* __restrict__ skip, int total4, float inv_n) {
    constexpr int C4 = DOUT / 4;
    __shared__ float sh_scale[DOUT], sh_shift[DOUT];
    if (threadIdx.x < DOUT) {
        int t = threadIdx.x;
        float mm = stats[t] * inv_n;
        float var = stats[DOUT + t] * inv_n - mm * mm;
        float sc = rsqrtf(var + BN_EPS) * gamma[t];
        sh_scale[t] = sc;
        sh_shift[t] = beta[t] - mm * sc;
    }
    __syncthreads();
    for (int idx = blockIdx.x * 256 + threadIdx.x; idx < total4; idx += gridDim.x * 256) {
        int c4 = (idx % C4) * 4;
        uint2 u = ((const uint2*)h)[idx];
        float v0 = bflo(u.x), v1 = bfhi(u.x), v2 = bflo(u.y), v3 = bfhi(u.y);
        v0 = fmaxf(fmaf(v0, sh_scale[c4 + 0], sh_shift[c4 + 0]), 0.f);
        v1 = fmaxf(fmaf(v1, sh_scale[c4 + 1], sh_shift[c4 + 1]), 0.f);
        v2 = fmaxf(fmaf(v2, sh_scale[c4 + 2], sh_shift[c4 + 2]), 0.f);
        v3 = fmaxf(fmaf(v3, sh_scale[c4 + 3], sh_shift[c4 + 3]), 0.f);
        if (SKIP) {
            uint2 sk = ((const uint2*)skip)[idx];
            v0 += bflo(sk.x); v1 += bfhi(sk.x); v2 += bflo(sk.y); v3 += bfhi(sk.y);
        }
        uint2 o; o.x = pack2(v0, v1); o.y = pack2(v2, v3);
        ((uint2*)h)[idx] = o;
    }
}

// ---------------------------------------------------------------------------
// graph boundaries from sorted segment_ids
// ---------------------------------------------------------------------------
__global__ void gstart_kernel(const int* __restrict__ seg, int* __restrict__ gstart,
                              int n, int g_count) {
    int i = blockIdx.x * 256 + threadIdx.x;
    if (i >= n) return;
    int cur = seg[i];
    if (i == 0) {
        for (int g = 0; g <= cur; ++g) gstart[g] = 0;
    } else {
        int prev = seg[i - 1];
        for (int g = prev + 1; g <= cur; ++g) gstart[g] = i;
    }
    if (i == n - 1) {
        for (int g = cur + 1; g <= g_count; ++g) gstart[g] = n;
    }
}

// ---------------------------------------------------------------------------
// pooling over RAW layer-5 output with fused BN affine + ReLU, PLUS fused
// agg-BN channel statistics (replaces the 4-block agg_stats kernel that was
// a hidden 127 µs latency-bound launch). aggstat[ch*2] = sum, [ch*2+1] = sumsq
// over graphs x features. Grid is exactly G/4 blocks, all waves active.
// ---------------------------------------------------------------------------
__global__ __launch_bounds__(256)
void pool_kernel(const u16* __restrict__ hraw, const float* __restrict__ stats,
                 const float* __restrict__ gamma, const float* __restrict__ beta,
                 const int* __restrict__ gstart, float* __restrict__ pooled,
                 float* __restrict__ aggstat, int g_count, float inv_n) {
    __shared__ float sagg[8];
    if (threadIdx.x < 8) sagg[threadIdx.x] = 0.f;
    __syncthreads();
    int wave = threadIdx.x >> 6;
    int lane = threadIdx.x & 63;
    int g = blockIdx.x * 4 + wave;
    if (g < g_count) {
        float mmean = stats[lane] * inv_n;
        float var = stats[64 + lane] * inv_n - mmean * mmean;
        float sc = rsqrtf(var + BN_EPS) * gamma[lane];
        float sh = beta[lane] - mmean * sc;
        int s = gstart[g], e = gstart[g + 1];
        float mx = -INFINITY, mn = INFINITY, sm = 0.f, sq = 0.f;
        for (int nidx = s; nidx < e; ++nidx) {
            float v = fmaxf(fmaf(bf1(hraw[(size_t)nidx * 64 + lane]), sc, sh), 0.f);
            mx = fmaxf(mx, v);
            mn = fminf(mn, v);
            sm += v;
            sq += v * v;
        }
        float cnt = (float)(e - s);
        float mean = sm / fmaxf(cnt, 1.f);
        float var2 = (sq - cnt * mean * mean) / fmaxf(cnt - 1.f, 1.f);
        float sd = sqrtf(fmaxf(var2, 0.f));
        size_t base = (size_t)g * 256;
        pooled[base + 0 * 64 + lane] = mx;
        pooled[base + 1 * 64 + lane] = mn;
        pooled[base + 2 * 64 + lane] = mean;
        pooled[base + 3 * 64 + lane] = sd;
        // wave-reduce channel sums/sumsqs for agg BN
        float s0 = mx, s1 = mn, s2 = mean, s3 = sd;
        float q0 = mx * mx, q1 = mn * mn, q2 = mean * mean, q3 = sd * sd;
        for (int off = 32; off > 0; off >>= 1) {
            s0 += __shfl_down(s0, off, 64); q0 += __shfl_down(q0, off, 64);
            s1 += __shfl_down(s1, off, 64); q1 += __shfl_down(q1, off, 64);
            s2 += __shfl_down(s2, off, 64); q2 += __shfl_down(q2, off, 64);
            s3 += __shfl_down(s3, off, 64); q3 += __shfl_down(q3, off, 64);
        }
        if (lane == 0) {
            atomicAdd(&sagg[0], s0); atomicAdd(&sagg[1], q0);
            atomicAdd(&sagg[2], s1); atomicAdd(&sagg[3], q1);
            atomicAdd(&sagg[4], s2); atomicAdd(&sagg[5], q2);
            atomicAdd(&sagg[6], s3); atomicAdd(&sagg[7], q3);
        }
    }
    __syncthreads();
    if (threadIdx.x < 8) atomicAdd(&aggstat[threadIdx.x], sagg[threadIdx.x]);
}

__global__ __launch_bounds__(256)
void final_kernel(const float* __restrict__ pooled, const float* __restrict__ aggstat,
                  const float* __restrict__ agg_gamma, const float* __restrict__ agg_beta,
                  const float* __restrict__ aggW, const float* __restrict__ aggb,
                  const float* __restrict__ outW, const float* __restrict__ outb,
                  float* __restrict__ out, int g_count, float inv_total) {
    __shared__ float sflat[4][256];
    int wave = threadIdx.x >> 6;
    int lane = threadIdx.x & 63;
    int g = blockIdx.x * 4 + wave;
    if (g < g_count) {
#pragma unroll
        for (int c = 0; c < 4; ++c) {
            float v = pooled[(size_t)g * 256 + c * 64 + lane];
            float m = aggstat[c * 2] * inv_total;
            float var = aggstat[c * 2 + 1] * inv_total - m * m;
            v = (v - m) * rsqrtf(var + BN_EPS) * agg_gamma[c] + agg_beta[c];
            sflat[wave][c * 64 + lane] = v;
        }
    }
    __syncthreads();
    if (g < g_count) {
        float acc = aggb[lane];
        const float* wrow = aggW + lane * 256;
#pragma unroll 8
        for (int i = 0; i < 256; ++i)
            acc = fmaf(sflat[wave][i], wrow[i], acc);
        float t = acc * outW[lane];
        for (int off = 32; off > 0; off >>= 1) t += __shfl_down(t, off, 64);
        if (lane == 0) out[g] = t + outb[0];
    }
}

// ---------------------------------------------------------------------------
// host launcher
// ---------------------------------------------------------------------------
extern "C" void kernel_launch(void* const* d_in, const int* in_sizes, int n_in,
                              void* d_out, int out_size, void* d_ws, size_t ws_size,
                              hipStream_t stream) {
    const int N = N_NODES, E = N_EDGES, G = N_GRAPHS;

    const float* x           = (const float*)d_in[0];
    const int*   ei          = (const int*)d_in[1];
    const int*   seg         = (const int*)d_in[2];
    const float* conv_W      = (const float*)d_in[3];
    const float* conv_W_last = (const float*)d_in[4];
    const float* bn_g        = (const float*)d_in[5];
    const float* bn_b        = (const float*)d_in[6];
    const float* bn_gl       = (const float*)d_in[7];
    const float* bn_bl       = (const float*)d_in[8];
    const float* agg_g       = (const float*)d_in[9];
    const float* agg_bt      = (const float*)d_in[10];
    const float* aggW        = (const float*)d_in[11];
    const float* aggb        = (const float*)d_in[12];
    const float* outW        = (const float*)d_in[13];
    const float* outb        = (const float*)d_in[14];
    float* out = (float*)d_out;

    const int* esrc = ei;
    const int* edst = ei + E;

    size_t off = 0;
    auto alloc = [&](size_t bytes) -> void* {
        void* p = (char*)d_ws + off;
        off += (bytes + 255) & ~(size_t)255;
        return p;
    };
    float* normv  = (float*)alloc((size_t)N * 4);
    int*   rowptr = (int*)alloc((size_t)(N + 1) * 4);
    int*   csr    = (int*)alloc((size_t)E * 4);
    int*   bcnt   = (int*)alloc((NB + 1) * 4);
    int*   bbase  = (int*)alloc((NB + 1) * 4);
    int*   bcur   = (int*)alloc((NB + 1) * 4);
    int*   gstart = (int*)alloc((size_t)(G + 1) * 4);
    float* statsA = (float*)alloc((6 * 256 + 8) * 4);   // per-layer BN sums + agg sums
    float* aggstat= statsA + 6 * 256;
    float* pooled = (float*)alloc((size_t)G * 256 * 4);
    const size_t WPACK = 5 * 384 * 128 + 384 * 64;
    u16*   whip   = (u16*)alloc(WPACK * 2);
    u16*   wlop   = (u16*)alloc(WPACK * 2);
    u16*   ring0  = (u16*)alloc((size_t)N * 128 * 2);
    u16*   ring1  = (u16*)alloc((size_t)N * 128 * 2);
    u16*   ring2  = (u16*)alloc((size_t)N * 128 * 2);
    u16*   p1     = (u16*)alloc((size_t)N * 128 * 2);
    u16*   p2     = (u16*)alloc((size_t)N * 128 * 2);
    u16*   ring[3] = {ring0, ring1, ring2};
    uint2* esorted = (uint2*)p2;   // alias: dead before first prop2 writes p2

    // ---- CSR build (multisplit) + norm ----
    hipMemsetAsync(bcnt, 0, (NB + 1) * 4, stream);
    hipMemsetAsync(statsA, 0, (6 * 256 + 8) * 4, stream);
    const int nchunk = (E + CHUNK - 1) / CHUNK;
    bucket_hist<<<nchunk, 256, 0, stream>>>(edst, bcnt, E);
    bucket_scan<<<1, 512, 0, stream>>>(bcnt, bbase, bcur);
    bucket_scatter<<<nchunk, 256, 0, stream>>>(esrc, edst, bcur, esorted, E);
    bucket_fill<<<NB, 256, 0, stream>>>(esorted, bbase, rowptr, csr, normv, N, E);

    // ---- x -> bf16 (into ring2; dead before layer 2 writes it) ----
    x2bf_kernel<<<2048, 256, 0, stream>>>(x, ring2, N * 128 / 4);

    // ---- W pack (single launch) ----
    wpack_all<<<(5 * 384 * 128 + 384 * 64 + 255) / 256, 256, 0, stream>>>(
        conv_W, conv_W_last, whip, wlop);

    // ---- graph boundaries ----
    gstart_kernel<<<(N + 255) / 256, 256, 0, stream>>>(seg, gstart, N, G);

    // ---- layers ----
    const u16* h_in = ring2;
    const int gemm_grid = (N + 127) / 128;
    const float inv_n = 1.f / (float)N;
    for (int l = 0; l < 6; ++l) {
        const int dout = (l < 5) ? 128 : 64;
        const u16* whi = whip + (size_t)((l < 5) ? l * 384 * 128 : 5 * 384 * 128);
        const u16* wlo = wlop + (size_t)((l < 5) ? l * 384 * 128 : 5 * 384 * 128);
        const float* gamma = (l < 5) ? (bn_g + l * 128) : bn_gl;
        const float* beta  = (l < 5) ? (bn_b + l * 128) : bn_bl;
        float* stats = statsA + l * 256;
        u16* outbuf = ring[l % 3];

        prop_kernel<<<(N + 3) / 4, 256, 0, stream>>>(h_in, normv, rowptr, csr, p1, N);
        prop_kernel<<<(N + 3) / 4, 256, 0, stream>>>(p1, normv, rowptr, csr, p2, N);

        if (dout == 128)
            gemm_mfma<128><<<gemm_grid, 256, 0, stream>>>(h_in, p1, p2, whi, wlo, outbuf,
                                                          stats, N);
        else
            gemm_mfma<64><<<gemm_grid, 256, 0, stream>>>(h_in, p1, p2, whi, wlo, outbuf,
                                                         stats, N);

        if (l < 5) {
            int total4 = N * dout / 4;
            bool has_skip = (l >= 2);
            const u16* skipb = has_skip ? ring[(l - 2) % 3] : nullptr;
            if (has_skip)
                bn_apply<128, true><<<8192, 256, 0, stream>>>(outbuf, stats, gamma, beta,
                                                              skipb, total4, inv_n);
            else
                bn_apply<128, false><<<8192, 256, 0, stream>>>(outbuf, stats, gamma, beta,
                                                               nullptr, total4, inv_n);
        }
        h_in = outbuf;
    }

    // ---- pooling (fused layer-5 BN affine + fused agg stats) + head ----
    pool_kernel<<<(G + 3) / 4, 256, 0, stream>>>(ring[5 % 3], statsA + 5 * 256,
                                                 bn_gl, bn_bl, gstart, pooled, aggstat,
                                                 G, inv_n);
    final_kernel<<<(G + 3) / 4, 256, 0, stream>>>(pooled, aggstat, agg_g, agg_bt,
                                                  aggW, aggb, outW, outb, out, G,
                                                  1.f / (float)(G * 64));
}

// Round 11
// 2552.549 us; speedup vs baseline: 1.2200x; 1.0221x over previous
//
#include <hip/hip_runtime.h>
#include <cstddef>
#include <cstdint>

#define N_NODES  200000
#define N_EDGES  3200000
#define N_GRAPHS 2000
#define BN_EPS   1e-5f
#define NB       391          // ceil(N / 512) buckets
#define BSH      9            // bucket = dst >> 9 (512 nodes per bucket)
#define CHUNK    16384        // edges per block in hist/scatter

typedef unsigned int   u32;
typedef unsigned short u16;

using short8   = __attribute__((ext_vector_type(8))) short;
using floatx16 = __attribute__((ext_vector_type(16))) float;

// ---------------------------------------------------------------------------
// bf16 helpers (raw-bit, RNE pack)
// ---------------------------------------------------------------------------
__device__ __forceinline__ float bflo(u32 v) { union {u32 i; float f;} c; c.i = v << 16; return c.f; }
__device__ __forceinline__ float bfhi(u32 v) { union {u32 i; float f;} c; c.i = v & 0xffff0000u; return c.f; }
__device__ __forceinline__ float bf1(u16 v)  { union {u32 i; float f;} c; c.i = ((u32)v) << 16; return c.f; }
__device__ __forceinline__ u32 f2bf(float f) {
    union {float f; u32 i;} c; c.f = f;
    return (c.i + 0x7fffu + ((c.i >> 16) & 1u)) >> 16;
}
__device__ __forceinline__ u32 pack2(float a, float b) { return f2bf(a) | (f2bf(b) << 16); }

// ---------------------------------------------------------------------------
// x (fp32) -> bf16
// ---------------------------------------------------------------------------
__global__ void x2bf_kernel(const float* __restrict__ x, u16* __restrict__ xb, int total4) {
    for (int i = blockIdx.x * 256 + threadIdx.x; i < total4; i += gridDim.x * 256) {
        float4 v = ((const float4*)x)[i];
        uint2 o; o.x = pack2(v.x, v.y); o.y = pack2(v.z, v.w);
        ((uint2*)xb)[i] = o;
    }
}

// ---------------------------------------------------------------------------
// W pack: layers 0-4 -> [6 chunks][128][64] (K=384). Layer 5 -> Wcat
// [2 chunks][192][64] (K=128, cols 0-63=W0, 64-127=W1, 128-191=W2) for the
// pre-propagation GEMM  z = h @ [W0|W1|W2].
// ---------------------------------------------------------------------------
__global__ void wpack_all(const float* __restrict__ convW, const float* __restrict__ convWlast,
                          u16* __restrict__ whi, u16* __restrict__ wlo) {
    const int PER = 384 * 128;
    int tid = blockIdx.x * 256 + threadIdx.x;
    float w;
    int dst;
    if (tid < 5 * PER) {
        int l = tid / PER, r = tid % PER;
        int k = r / 128, nn = r % 128;
        w = convW[tid];
        dst = l * PER + (k >> 6) * 128 * 64 + nn * 64 + (k & 63);
    } else {
        int r = tid - 5 * PER;
        if (r >= 128 * 192) return;
        int k = r / 192, n = r % 192;          // k in 0..127, n in 0..191
        int j = n >> 6, c = n & 63;            // which W slice, col within
        w = convWlast[(128 * j + k) * 64 + c];
        dst = 5 * PER + (k >> 6) * 192 * 64 + n * 64 + (k & 63);
    }
    u16 hi = (u16)f2bf(w);
    float rem = w - bf1(hi);
    whi[dst] = hi;
    wlo[dst] = (u16)f2bf(rem);
}

// ---------------------------------------------------------------------------
// CSR build via 391-bucket multisplit (bucket = dst >> 9)
// ---------------------------------------------------------------------------
__global__ __launch_bounds__(256)
void bucket_hist(const int* __restrict__ edst, int* __restrict__ bcnt, int e) {
    __shared__ int h[NB];
    for (int t = threadIdx.x; t < NB; t += 256) h[t] = 0;
    __syncthreads();
    int base = blockIdx.x * CHUNK;
    int end  = min(base + CHUNK, e);
    for (int i = base + threadIdx.x; i < end; i += 256)
        atomicAdd(&h[edst[i] >> BSH], 1);
    __syncthreads();
    for (int t = threadIdx.x; t < NB; t += 256)
        if (h[t]) atomicAdd(&bcnt[t], h[t]);
}

__global__ void bucket_scan(const int* __restrict__ bcnt, int* __restrict__ bbase,
                            int* __restrict__ bcur) {
    __shared__ int ls[512];
    int t = threadIdx.x;
    int v = (t < NB) ? bcnt[t] : 0;
    ls[t] = v;
    __syncthreads();
    for (int off = 1; off < 512; off <<= 1) {
        int a = (t >= off) ? ls[t - off] : 0;
        __syncthreads();
        ls[t] += a;
        __syncthreads();
    }
    if (t <= NB) {
        int excl = ls[t] - v;
        bbase[t] = excl;
        if (t < NB) bcur[t] = excl;
    }
}

__global__ __launch_bounds__(256)
void bucket_scatter(const int* __restrict__ esrc, const int* __restrict__ edst,
                    int* __restrict__ bcur, uint2* __restrict__ esorted, int e) {
    __shared__ int h[NB], lbase[NB], lcur[NB];
    for (int t = threadIdx.x; t < NB; t += 256) { h[t] = 0; lcur[t] = 0; }
    __syncthreads();
    int base = blockIdx.x * CHUNK;
    int end  = min(base + CHUNK, e);
    for (int i = base + threadIdx.x; i < end; i += 256)
        atomicAdd(&h[edst[i] >> BSH], 1);
    __syncthreads();
    for (int t = threadIdx.x; t < NB; t += 256)
        lbase[t] = h[t] ? atomicAdd(&bcur[t], h[t]) : 0;
    __syncthreads();
    for (int i = base + threadIdx.x; i < end; i += 256) {
        int d = edst[i];
        int b = d >> BSH;
        int p = lbase[b] + atomicAdd(&lcur[b], 1);
        uint2 ed; ed.x = (u32)esrc[i]; ed.y = (u32)d;
        esorted[p] = ed;
    }
}

// One block per bucket: local count -> scan -> rowptr + norm -> CSR fill.
// (No adjacency sort: round-8 measured +170 µs cost, ~0 prop gain.)
__global__ __launch_bounds__(256)
void bucket_fill(const uint2* __restrict__ esorted, const int* __restrict__ bbase,
                 int* __restrict__ rowptr, int* __restrict__ csr,
                 float* __restrict__ normv, int n, int e) {
    __shared__ int cnt[512], loc[512], tsum[256];
    const int b = blockIdx.x;
    const int ebeg = bbase[b], eend = bbase[b + 1];
    const int t = threadIdx.x;
    cnt[t] = 0; cnt[t + 256] = 0;
    __syncthreads();
    for (int i = ebeg + t; i < eend; i += 256)
        atomicAdd(&cnt[esorted[i].y & 511], 1);
    __syncthreads();
    int c0 = cnt[2 * t], c1 = cnt[2 * t + 1];
    tsum[t] = c0 + c1;
    __syncthreads();
    for (int off = 1; off < 256; off <<= 1) {
        int a = (t >= off) ? tsum[t - off] : 0;
        __syncthreads();
        tsum[t] += a;
        __syncthreads();
    }
    int excl = tsum[t] - (c0 + c1);
    loc[2 * t] = excl;
    loc[2 * t + 1] = excl + c0;
    __syncthreads();
    for (int j = t; j < 512; j += 256) {
        int node = (b << 9) + j;
        if (node < n) {
            rowptr[node] = ebeg + loc[j];
            int deg = cnt[j];
            normv[node] = (deg > 0) ? rsqrtf((float)deg) : 0.f;
        }
    }
    if (b == 0 && t == 0) rowptr[n] = e;
    __syncthreads();
    for (int j = t; j < 512; j += 256) cnt[j] = loc[j];
    __syncthreads();
    for (int i = ebeg + t; i < eend; i += 256) {
        uint2 ed = esorted[i];
        int slot = ebeg + atomicAdd(&cnt[ed.y & 511], 1);
        csr[slot] = (int)ed.x;
    }
}

// ---------------------------------------------------------------------------
// prop, 128-dim (layers 0-4; measured floor 129.8 µs — ILP/order/footprint
// variants all neutral or worse): quarter-wave gather, 16 edges/iter.
// ---------------------------------------------------------------------------
__global__ __launch_bounds__(256)
void prop_kernel(const u16* __restrict__ hin, const float* __restrict__ norm,
                 const int* __restrict__ rowptr, const int* __restrict__ csr,
                 u16* __restrict__ pout, int n) {
    int wave = threadIdx.x >> 6;
    int lane = threadIdx.x & 63;
    int node = blockIdx.x * 4 + wave;
    if (node >= n) return;
    const int q = lane >> 4;
    const int f = (lane & 15) * 8;
    int s = rowptr[node], e = rowptr[node + 1];
    float a0 = 0, a1 = 0, a2 = 0, a3 = 0, a4 = 0, a5 = 0, a6 = 0, a7 = 0;
    int i = s + q;
    if (i + 12 < e) {
        int sn0 = csr[i], sn1 = csr[i + 4], sn2 = csr[i + 8], sn3 = csr[i + 12];
        while (true) {
            float nw0 = norm[sn0], nw1 = norm[sn1], nw2 = norm[sn2], nw3 = norm[sn3];
            uint4 v0 = *(const uint4*)(hin + (size_t)sn0 * 128 + f);
            uint4 v1 = *(const uint4*)(hin + (size_t)sn1 * 128 + f);
            uint4 v2 = *(const uint4*)(hin + (size_t)sn2 * 128 + f);
            uint4 v3 = *(const uint4*)(hin + (size_t)sn3 * 128 + f);
            int ni = i + 16;
            bool more = (ni + 12 < e);
            int t0 = 0, t1 = 0, t2 = 0, t3 = 0;
            if (more) {
                t0 = csr[ni]; t1 = csr[ni + 4]; t2 = csr[ni + 8]; t3 = csr[ni + 12];
            }
            a0 += bflo(v0.x) * nw0 + bflo(v1.x) * nw1 + bflo(v2.x) * nw2 + bflo(v3.x) * nw3;
            a1 += bfhi(v0.x) * nw0 + bfhi(v1.x) * nw1 + bfhi(v2.x) * nw2 + bfhi(v3.x) * nw3;
            a2 += bflo(v0.y) * nw0 + bflo(v1.y) * nw1 + bflo(v2.y) * nw2 + bflo(v3.y) * nw3;
            a3 += bfhi(v0.y) * nw0 + bfhi(v1.y) * nw1 + bfhi(v2.y) * nw2 + bfhi(v3.y) * nw3;
            a4 += bflo(v0.z) * nw0 + bflo(v1.z) * nw1 + bflo(v2.z) * nw2 + bflo(v3.z) * nw3;
            a5 += bfhi(v0.z) * nw0 + bfhi(v1.z) * nw1 + bfhi(v2.z) * nw2 + bfhi(v3.z) * nw3;
            a6 += bflo(v0.w) * nw0 + bflo(v1.w) * nw1 + bflo(v2.w) * nw2 + bflo(v3.w) * nw3;
            a7 += bfhi(v0.w) * nw0 + bfhi(v1.w) * nw1 + bfhi(v2.w) * nw2 + bfhi(v3.w) * nw3;
            i = ni;
            if (!more) break;
            sn0 = t0; sn1 = t1; sn2 = t2; sn3 = t3;
        }
    }
    for (; i < e; i += 4) {
        int sn0 = csr[i];
        float nw0 = norm[sn0];
        uint4 v0 = *(const uint4*)(hin + (size_t)sn0 * 128 + f);
        a0 += bflo(v0.x) * nw0; a1 += bfhi(v0.x) * nw0;
        a2 += bflo(v0.y) * nw0; a3 += bfhi(v0.y) * nw0;
        a4 += bflo(v0.z) * nw0; a5 += bfhi(v0.z) * nw0;
        a6 += bflo(v0.w) * nw0; a7 += bfhi(v0.w) * nw0;
    }
    a0 += __shfl_down(a0, 32, 64); a1 += __shfl_down(a1, 32, 64);
    a2 += __shfl_down(a2, 32, 64); a3 += __shfl_down(a3, 32, 64);
    a4 += __shfl_down(a4, 32, 64); a5 += __shfl_down(a5, 32, 64);
    a6 += __shfl_down(a6, 32, 64); a7 += __shfl_down(a7, 32, 64);
    a0 += __shfl_down(a0, 16, 64); a1 += __shfl_down(a1, 16, 64);
    a2 += __shfl_down(a2, 16, 64); a3 += __shfl_down(a3, 16, 64);
    a4 += __shfl_down(a4, 16, 64); a5 += __shfl_down(a5, 16, 64);
    a6 += __shfl_down(a6, 16, 64); a7 += __shfl_down(a7, 16, 64);
    if (q == 0) {
        float nd = norm[node];
        uint4 o;
        o.x = pack2(a0 * nd, a1 * nd);
        o.y = pack2(a2 * nd, a3 * nd);
        o.z = pack2(a4 * nd, a5 * nd);
        o.w = pack2(a6 * nd, a7 * nd);
        *(uint4*)(pout + (size_t)node * 128 + f) = o;
    }
}

// ---------------------------------------------------------------------------
// prop64: 64-dim propagation with fused add (layer 5 restructure:
// out[node] = add[node] + norm[node] * sum norm[src]*zin[src]).
// Row = 128 B; lane = edge_slot(8) x fgroup(8); strides parameterized so zin
// can be a 64-col slice of the 192-col z matrix.
// ---------------------------------------------------------------------------
__global__ __launch_bounds__(256)
void prop64(const u16* __restrict__ zin, int zstride,
            const u16* __restrict__ addin, int astride,
            const float* __restrict__ norm,
            const int* __restrict__ rowptr, const int* __restrict__ csr,
            u16* __restrict__ outp, int n) {
    int wave = threadIdx.x >> 6;
    int lane = threadIdx.x & 63;
    int node = blockIdx.x * 4 + wave;
    if (node >= n) return;
    const int e8 = lane >> 3;                 // edge slot 0..7
    const int f  = (lane & 7) * 8;            // feature offset (bf16 units)
    int s = rowptr[node], e = rowptr[node + 1];
    float a0 = 0, a1 = 0, a2 = 0, a3 = 0, a4 = 0, a5 = 0, a6 = 0, a7 = 0;
    int ib = s;
    if (ib + 16 <= e) {
        int sn0 = csr[ib + e8], sn1 = csr[ib + 8 + e8];
        while (true) {
            float nw0 = norm[sn0], nw1 = norm[sn1];
            uint4 v0 = *(const uint4*)(zin + (size_t)sn0 * zstride + f);
            uint4 v1 = *(const uint4*)(zin + (size_t)sn1 * zstride + f);
            int nb = ib + 16;
            bool more = (nb + 16 <= e);
            int t0 = 0, t1 = 0;
            if (more) { t0 = csr[nb + e8]; t1 = csr[nb + 8 + e8]; }
            a0 += bflo(v0.x) * nw0 + bflo(v1.x) * nw1;
            a1 += bfhi(v0.x) * nw0 + bfhi(v1.x) * nw1;
            a2 += bflo(v0.y) * nw0 + bflo(v1.y) * nw1;
            a3 += bfhi(v0.y) * nw0 + bfhi(v1.y) * nw1;
            a4 += bflo(v0.z) * nw0 + bflo(v1.z) * nw1;
            a5 += bfhi(v0.z) * nw0 + bfhi(v1.z) * nw1;
            a6 += bflo(v0.w) * nw0 + bflo(v1.w) * nw1;
            a7 += bfhi(v0.w) * nw0 + bfhi(v1.w) * nw1;
            ib = nb;
            if (!more) break;
            sn0 = t0; sn1 = t1;
        }
    }
    if (ib + e8 < e) {
        int sn = csr[ib + e8];
        float nw = norm[sn];
        uint4 v = *(const uint4*)(zin + (size_t)sn * zstride + f);
        a0 += bflo(v.x) * nw; a1 += bfhi(v.x) * nw;
        a2 += bflo(v.y) * nw; a3 += bfhi(v.y) * nw;
        a4 += bflo(v.z) * nw; a5 += bfhi(v.z) * nw;
        a6 += bflo(v.w) * nw; a7 += bfhi(v.w) * nw;
    }
    if (ib + 8 + e8 < e) {
        int sn = csr[ib + 8 + e8];
        float nw = norm[sn];
        uint4 v = *(const uint4*)(zin + (size_t)sn * zstride + f);
        a0 += bflo(v.x) * nw; a1 += bfhi(v.x) * nw;
        a2 += bflo(v.y) * nw; a3 += bfhi(v.y) * nw;
        a4 += bflo(v.z) * nw; a5 += bfhi(v.z) * nw;
        a6 += bflo(v.w) * nw; a7 += bfhi(v.w) * nw;
    }
    a0 += __shfl_down(a0, 32, 64); a1 += __shfl_down(a1, 32, 64);
    a2 += __shfl_down(a2, 32, 64); a3 += __shfl_down(a3, 32, 64);
    a4 += __shfl_down(a4, 32, 64); a5 += __shfl_down(a5, 32, 64);
    a6 += __shfl_down(a6, 32, 64); a7 += __shfl_down(a7, 32, 64);
    a0 += __shfl_down(a0, 16, 64); a1 += __shfl_down(a1, 16, 64);
    a2 += __shfl_down(a2, 16, 64); a3 += __shfl_down(a3, 16, 64);
    a4 += __shfl_down(a4, 16, 64); a5 += __shfl_down(a5, 16, 64);
    a6 += __shfl_down(a6, 16, 64); a7 += __shfl_down(a7, 16, 64);
    a0 += __shfl_down(a0, 8, 64);  a1 += __shfl_down(a1, 8, 64);
    a2 += __shfl_down(a2, 8, 64);  a3 += __shfl_down(a3, 8, 64);
    a4 += __shfl_down(a4, 8, 64);  a5 += __shfl_down(a5, 8, 64);
    a6 += __shfl_down(a6, 8, 64);  a7 += __shfl_down(a7, 8, 64);
    if (e8 == 0) {
        float nd = norm[node];
        uint4 ad = *(const uint4*)(addin + (size_t)node * astride + f);
        uint4 o;
        o.x = pack2(bflo(ad.x) + a0 * nd, bfhi(ad.x) + a1 * nd);
        o.y = pack2(bflo(ad.y) + a2 * nd, bfhi(ad.y) + a3 * nd);
        o.z = pack2(bflo(ad.z) + a4 * nd, bfhi(ad.z) + a5 * nd);
        o.w = pack2(bflo(ad.w) + a6 * nd, bfhi(ad.w) + a7 * nd);
        *(uint4*)(outp + (size_t)node * 64 + f) = o;
    }
}

// ---------------------------------------------------------------------------
// MFMA GEMM + fused BN stats, layers 0-4 (direct global->LDS staging;
// register-prefetch variant spilled to scratch — do not reintroduce)
// ---------------------------------------------------------------------------
template <int DOUT>
__global__ __launch_bounds__(256)
void gemm_mfma(const u16* __restrict__ A0, const u16* __restrict__ A1,
               const u16* __restrict__ A2, const u16* __restrict__ whi,
               const u16* __restrict__ wlo, u16* __restrict__ outp,
               float* __restrict__ gstats, int n) {
    constexpr int TJ = DOUT / 64;
    constexpr int BELEMS = DOUT * 64;
    __shared__ u16 As[128 * 64];
    __shared__ u16 Bh[BELEMS];
    __shared__ u16 Bl[BELEMS];
    __shared__ float col_s[DOUT];
    __shared__ float col_q[DOUT];

    const int tid  = threadIdx.x;
    const int wave = tid >> 6;
    const int lane = tid & 63;
    const int wrow = wave >> 1;
    const int wcol = wave & 1;
    const int row0 = blockIdx.x * 128;
    const int m    = lane & 31;
    const int half = lane >> 5;

    const u16* mats[3] = {A0, A1, A2};

    floatx16 acc[2][TJ];
#pragma unroll
    for (int ti = 0; ti < 2; ++ti)
#pragma unroll
        for (int tj = 0; tj < TJ; ++tj)
#pragma unroll
            for (int r = 0; r < 16; ++r) acc[ti][tj][r] = 0.f;

    for (int c = 0; c < 6; ++c) {
        const u16* M = mats[c >> 1];
        const int kloc = (c & 1) * 64;
#pragma unroll
        for (int it = 0; it < 4; ++it) {
            int rib  = wave * 32 + it * 8 + (lane >> 3);
            int grow = row0 + rib;
            if (grow >= n) grow = n - 1;
            uint4 v = *(const uint4*)(M + (size_t)grow * 128 + kloc + (lane & 7) * 8);
            int cc = (lane & 7) ^ (rib & 7);
            *(uint4*)&As[rib * 64 + cc * 8] = v;
        }
        {
            const int cbase = c * BELEMS;
#pragma unroll
            for (int j = 0; j < BELEMS / 2048; ++j) {
                int idx  = tid + j * 256;
                int nrow = idx >> 3, seg = idx & 7;
                int dcc  = seg ^ (nrow & 7);
                *(uint4*)&Bh[nrow * 64 + dcc * 8] =
                    *(const uint4*)(whi + cbase + idx * 8);
                *(uint4*)&Bl[nrow * 64 + dcc * 8] =
                    *(const uint4*)(wlo + cbase + idx * 8);
            }
        }
        __syncthreads();
#pragma unroll
        for (int s = 0; s < 4; ++s) {
            const int cc = s * 2 + half;
            short8 a[2], bhf[TJ], blf[TJ];
#pragma unroll
            for (int ti = 0; ti < 2; ++ti) {
                int r = wrow * 64 + ti * 32 + m;
                a[ti] = *(const short8*)&As[r * 64 + ((cc ^ (r & 7)) * 8)];
            }
#pragma unroll
            for (int tj = 0; tj < TJ; ++tj) {
                int rr = wcol * TJ * 32 + tj * 32 + m;
                int off = rr * 64 + ((cc ^ (rr & 7)) * 8);
                bhf[tj] = *(const short8*)&Bh[off];
                blf[tj] = *(const short8*)&Bl[off];
            }
#pragma unroll
            for (int ti = 0; ti < 2; ++ti)
#pragma unroll
                for (int tj = 0; tj < TJ; ++tj) {
                    acc[ti][tj] = __builtin_amdgcn_mfma_f32_32x32x16_bf16(
                        a[ti], bhf[tj], acc[ti][tj], 0, 0, 0);
                    acc[ti][tj] = __builtin_amdgcn_mfma_f32_32x32x16_bf16(
                        a[ti], blf[tj], acc[ti][tj], 0, 0, 0);
                }
        }
        __syncthreads();
    }

    if (tid < DOUT) { col_s[tid] = 0.f; col_q[tid] = 0.f; }
    __syncthreads();
#pragma unroll
    for (int tj = 0; tj < TJ; ++tj) {
        int gcol = (wcol * TJ + tj) * 32 + m;
        float s = 0.f, qq = 0.f;
#pragma unroll
        for (int ti = 0; ti < 2; ++ti)
#pragma unroll
            for (int r = 0; r < 16; ++r) {
                int grow = row0 + wrow * 64 + ti * 32 + (r & 3) + 8 * (r >> 2) + 4 * half;
                if (grow < n) {
                    float v = acc[ti][tj][r];
                    s += v; qq += v * v;
                    outp[(size_t)grow * DOUT + gcol] = (u16)f2bf(v);
                }
            }
        atomicAdd(&col_s[gcol], s);
        atomicAdd(&col_q[gcol], qq);
    }
    __syncthreads();
    if (tid < DOUT) {
        atomicAdd(&gstats[tid], col_s[tid]);
        atomicAdd(&gstats[DOUT + tid], col_q[tid]);
    }
}

// ---------------------------------------------------------------------------
// Layer-5 pre-propagation GEMM: z[N,192] = h[N,128] @ Wcat[128,192].
// 64-row tiles, 4 waves (2x2), wave = 32 rows x 96 cols. K=128 in 2 chunks.
// LDS: 8 + 24 + 24 KB = 56 KB.
// ---------------------------------------------------------------------------
__global__ __launch_bounds__(256)
void gemm192(const u16* __restrict__ A, const u16* __restrict__ whi,
             const u16* __restrict__ wlo, u16* __restrict__ z, int n) {
    __shared__ u16 As[64 * 64];
    __shared__ u16 Bh[192 * 64];
    __shared__ u16 Bl[192 * 64];

    const int tid  = threadIdx.x;
    const int wave = tid >> 6;
    const int lane = tid & 63;
    const int wrow = wave >> 1;
    const int wcol = wave & 1;
    const int row0 = blockIdx.x * 64;
    const int m    = lane & 31;
    const int half = lane >> 5;

    floatx16 acc[3];
#pragma unroll
    for (int tj = 0; tj < 3; ++tj)
#pragma unroll
        for (int r = 0; r < 16; ++r) acc[tj][r] = 0.f;

    for (int c = 0; c < 2; ++c) {
        const int kloc = c * 64;
#pragma unroll
        for (int it = 0; it < 2; ++it) {
            int rib  = it * 32 + (tid >> 3);
            int grow = row0 + rib;
            if (grow >= n) grow = n - 1;
            uint4 v = *(const uint4*)(A + (size_t)grow * 128 + kloc + (tid & 7) * 8);
            int cc = (tid & 7) ^ (rib & 7);
            *(uint4*)&As[rib * 64 + cc * 8] = v;
        }
        {
            const int cbase = c * 192 * 64;
#pragma unroll
            for (int j = 0; j < 6; ++j) {
                int idx  = tid + j * 256;
                int nrow = idx >> 3, seg = idx & 7;
                int dcc  = seg ^ (nrow & 7);
                *(uint4*)&Bh[nrow * 64 + dcc * 8] =
                    *(const uint4*)(whi + cbase + idx * 8);
                *(uint4*)&Bl[nrow * 64 + dcc * 8] =
                    *(const uint4*)(wlo + cbase + idx * 8);
            }
        }
        __syncthreads();
#pragma unroll
        for (int s = 0; s < 4; ++s) {
            const int cc = s * 2 + half;
            short8 a, bhf[3], blf[3];
            {
                int r = wrow * 32 + m;
                a = *(const short8*)&As[r * 64 + ((cc ^ (r & 7)) * 8)];
            }
#pragma unroll
            for (int tj = 0; tj < 3; ++tj) {
                int rr = wcol * 96 + tj * 32 + m;
                int off = rr * 64 + ((cc ^ (rr & 7)) * 8);
                bhf[tj] = *(const short8*)&Bh[off];
                blf[tj] = *(const short8*)&Bl[off];
            }
#pragma unroll
            for (int tj = 0; tj < 3; ++tj) {
                acc[tj] = __builtin_amdgcn_mfma_f32_32x32x16_bf16(a, bhf[tj], acc[tj], 0, 0, 0);
                acc[tj] = __builtin_amdgcn_mfma_f32_32x32x16_bf16(a, blf[tj], acc[tj], 0, 0, 0);
            }
        }
        __syncthreads();
    }
#pragma unroll
    for (int tj = 0; tj < 3; ++tj) {
        int gcol = wcol * 96 + tj * 32 + m;
#pragma unroll
        for (int r = 0; r < 16; ++r) {
            int grow = row0 + wrow * 32 + (r & 3) + 8 * (r >> 2) + 4 * half;
            if (grow < n)
                z[(size_t)grow * 192 + gcol] = (u16)f2bf(acc[tj][r]);
        }
    }
}

// ---------------------------------------------------------------------------
// BN stats for the 64-dim layer-5 output (raw column sums/sumsqs)
// ---------------------------------------------------------------------------
__global__ __launch_bounds__(256)
void bn_stats64(const u16* __restrict__ h, float* __restrict__ stats, int total4) {
    float s[4] = {0, 0, 0, 0}, q[4] = {0, 0, 0, 0};
    for (int idx = blockIdx.x * 256 + threadIdx.x; idx < total4; idx += gridDim.x * 256) {
        uint2 u = ((const uint2*)h)[idx];
        float v0 = bflo(u.x), v1 = bfhi(u.x), v2 = bflo(u.y), v3 = bfhi(u.y);
        s[0] += v0; q[0] += v0 * v0;
        s[1] += v1; q[1] += v1 * v1;
        s[2] += v2; q[2] += v2 * v2;
        s[3] += v3; q[3] += v3 * v3;
    }
    __shared__ float ls[256][4], lq[256][4];
#pragma unroll
    for (int j = 0; j < 4; ++j) { ls[threadIdx.x][j] = s[j]; lq[threadIdx.x][j] = q[j]; }
    __syncthreads();
    int t = threadIdx.x;
    if (t < 16) {
#pragma unroll 1
        for (int g = 1; g < 16; ++g) {
#pragma unroll
            for (int j = 0; j < 4; ++j) { s[j] += ls[t + g * 16][j]; q[j] += lq[t + g * 16][j]; }
        }
#pragma unroll
        for (int j = 0; j < 4; ++j) {
            atomicAdd(&stats[t * 4 + j], s[j]);
            atomicAdd(&stats[64 + t * 4 + j], q[j]);
        }
    }
}

// ---------------------------------------------------------------------------
// BN apply with inline finalize (scale/shift from raw sums per block)
// ---------------------------------------------------------------------------
template <int DOUT, bool SKIP>
__global__ __launch_bounds__(256)
void bn_apply(u16* __restrict__ h, const float* __restrict__ stats,
              const float* __restrict__ gamma, const float* __restrict__ beta,
              const u16* __restrict__ skip, int total4, float inv_n) {
    constexpr int C4 = DOUT / 4;
    __shared__ float sh_scale[DOUT], sh_shift[DOUT];
    if (threadIdx.x < DOUT) {
        int t = threadIdx.x;
        float mm = stats[t] * inv_n;
        float var = stats[DOUT + t] * inv_n - mm * mm;
        float sc = rsqrtf(var + BN_EPS) * gamma[t];
        sh_scale[t] = sc;
        sh_shift[t] = beta[t] - mm * sc;
    }
    __syncthreads();
    for (int idx = blockIdx.x * 256 + threadIdx.x; idx < total4; idx += gridDim.x * 256) {
        int c4 = (idx % C4) * 4;
        uint2 u = ((const uint2*)h)[idx];
        float v0 = bflo(u.x), v1 = bfhi(u.x), v2 = bflo(u.y), v3 = bfhi(u.y);
        v0 = fmaxf(fmaf(v0, sh_scale[c4 + 0], sh_shift[c4 + 0]), 0.f);
        v1 = fmaxf(fmaf(v1, sh_scale[c4 + 1], sh_shift[c4 + 1]), 0.f);
        v2 = fmaxf(fmaf(v2, sh_scale[c4 + 2], sh_shift[c4 + 2]), 0.f);
        v3 = fmaxf(fmaf(v3, sh_scale[c4 + 3], sh_shift[c4 + 3]), 0.f);
        if (SKIP) {
            uint2 sk = ((const uint2*)skip)[idx];
            v0 += bflo(sk.x); v1 += bfhi(sk.x); v2 += bflo(sk.y); v3 += bfhi(sk.y);
        }
        uint2 o; o.x = pack2(v0, v1); o.y = pack2(v2, v3);
        ((uint2*)h)[idx] = o;
    }
}

// ---------------------------------------------------------------------------
// graph boundaries from sorted segment_ids
// ---------------------------------------------------------------------------
__global__ void gstart_kernel(const int* __restrict__ seg, int* __restrict__ gstart,
                              int n, int g_count) {
    int i = blockIdx.x * 256 + threadIdx.x;
    if (i >= n) return;
    int cur = seg[i];
    if (i == 0) {
        for (int g = 0; g <= cur; ++g) gstart[g] = 0;
    } else {
        int prev = seg[i - 1];
        for (int g = prev + 1; g <= cur; ++g) gstart[g] = i;
    }
    if (i == n - 1) {
        for (int g = cur + 1; g <= g_count; ++g) gstart[g] = n;
    }
}

// ---------------------------------------------------------------------------
// pooling over RAW layer-5 output with fused BN affine + ReLU + fused agg-BN
// channel stats (aggstat[ch*2]=sum, [ch*2+1]=sumsq over graphs x features)
// ---------------------------------------------------------------------------
__global__ __launch_bounds__(256)
void pool_kernel(const u16* __restrict__ hraw, const float* __restrict__ stats,
                 const float* __restrict__ gamma, const float* __restrict__ beta,
                 const int* __restrict__ gstart, float* __restrict__ pooled,
                 float* __restrict__ aggstat, int g_count, float inv_n) {
    __shared__ float sagg[8];
    if (threadIdx.x < 8) sagg[threadIdx.x] = 0.f;
    __syncthreads();
    int wave = threadIdx.x >> 6;
    int lane = threadIdx.x & 63;
    int g = blockIdx.x * 4 + wave;
    if (g < g_count) {
        float mmean = stats[lane] * inv_n;
        float var = stats[64 + lane] * inv_n - mmean * mmean;
        float sc = rsqrtf(var + BN_EPS) * gamma[lane];
        float sh = beta[lane] - mmean * sc;
        int s = gstart[g], e = gstart[g + 1];
        float mx = -INFINITY, mn = INFINITY, sm = 0.f, sq = 0.f;
        for (int nidx = s; nidx < e; ++nidx) {
            float v = fmaxf(fmaf(bf1(hraw[(size_t)nidx * 64 + lane]), sc, sh), 0.f);
            mx = fmaxf(mx, v);
            mn = fminf(mn, v);
            sm += v;
            sq += v * v;
        }
        float cnt = (float)(e - s);
        float mean = sm / fmaxf(cnt, 1.f);
        float var2 = (sq - cnt * mean * mean) / fmaxf(cnt - 1.f, 1.f);
        float sd = sqrtf(fmaxf(var2, 0.f));
        size_t base = (size_t)g * 256;
        pooled[base + 0 * 64 + lane] = mx;
        pooled[base + 1 * 64 + lane] = mn;
        pooled[base + 2 * 64 + lane] = mean;
        pooled[base + 3 * 64 + lane] = sd;
        float s0 = mx, s1 = mn, s2 = mean, s3 = sd;
        float q0 = mx * mx, q1 = mn * mn, q2 = mean * mean, q3 = sd * sd;
        for (int off = 32; off > 0; off >>= 1) {
            s0 += __shfl_down(s0, off, 64); q0 += __shfl_down(q0, off, 64);
            s1 += __shfl_down(s1, off, 64); q1 += __shfl_down(q1, off, 64);
            s2 += __shfl_down(s2, off, 64); q2 += __shfl_down(q2, off, 64);
            s3 += __shfl_down(s3, off, 64); q3 += __shfl_down(q3, off, 64);
        }
        if (lane == 0) {
            atomicAdd(&sagg[0], s0); atomicAdd(&sagg[1], q0);
            atomicAdd(&sagg[2], s1); atomicAdd(&sagg[3], q1);
            atomicAdd(&sagg[4], s2); atomicAdd(&sagg[5], q2);
            atomicAdd(&sagg[6], s3); atomicAdd(&sagg[7], q3);
        }
    }
    __syncthreads();
    if (threadIdx.x < 8) atomicAdd(&aggstat[threadIdx.x], sagg[threadIdx.x]);
}

__global__ __launch_bounds__(256)
void final_kernel(const float* __restrict__ pooled, const float* __restrict__ aggstat,
                  const float* __restrict__ agg_gamma, const float* __restrict__ agg_beta,
                  const float* __restrict__ aggW, const float* __restrict__ aggb,
                  const float* __restrict__ outW, const float* __restrict__ outb,
                  float* __restrict__ out, int g_count, float inv_total) {
    __shared__ float sflat[4][256];
    int wave = threadIdx.x >> 6;
    int lane = threadIdx.x & 63;
    int g = blockIdx.x * 4 + wave;
    if (g < g_count) {
#pragma unroll
        for (int c = 0; c < 4; ++c) {
            float v = pooled[(size_t)g * 256 + c * 64 + lane];
            float m = aggstat[c * 2] * inv_total;
            float var = aggstat[c * 2 + 1] * inv_total - m * m;
            v = (v - m) * rsqrtf(var + BN_EPS) * agg_gamma[c] + agg_beta[c];
            sflat[wave][c * 64 + lane] = v;
        }
    }
    __syncthreads();
    if (g < g_count) {
        float acc = aggb[lane];
        const float* wrow = aggW + lane * 256;
#pragma unroll 8
        for (int i = 0; i < 256; ++i)
            acc = fmaf(sflat[wave][i], wrow[i], acc);
        float t = acc * outW[lane];
        for (int off = 32; off > 0; off >>= 1) t += __shfl_down(t, off, 64);
        if (lane == 0) out[g] = t + outb[0];
    }
}

// ---------------------------------------------------------------------------
// host launcher
// ---------------------------------------------------------------------------
extern "C" void kernel_launch(void* const* d_in, const int* in_sizes, int n_in,
                              void* d_out, int out_size, void* d_ws, size_t ws_size,
                              hipStream_t stream) {
    const int N = N_NODES, E = N_EDGES, G = N_GRAPHS;

    const float* x           = (const float*)d_in[0];
    const int*   ei          = (const int*)d_in[1];
    const int*   seg         = (const int*)d_in[2];
    const float* conv_W      = (const float*)d_in[3];
    const float* conv_W_last = (const float*)d_in[4];
    const float* bn_g        = (const float*)d_in[5];
    const float* bn_b        = (const float*)d_in[6];
    const float* bn_gl       = (const float*)d_in[7];
    const float* bn_bl       = (const float*)d_in[8];
    const float* agg_g       = (const float*)d_in[9];
    const float* agg_bt      = (const float*)d_in[10];
    const float* aggW        = (const float*)d_in[11];
    const float* aggb        = (const float*)d_in[12];
    const float* outW        = (const float*)d_in[13];
    const float* outb        = (const float*)d_in[14];
    float* out = (float*)d_out;

    const int* esrc = ei;
    const int* edst = ei + E;

    size_t off = 0;
    auto alloc = [&](size_t bytes) -> void* {
        void* p = (char*)d_ws + off;
        off += (bytes + 255) & ~(size_t)255;
        return p;
    };
    float* normv  = (float*)alloc((size_t)N * 4);
    int*   rowptr = (int*)alloc((size_t)(N + 1) * 4);
    int*   csr    = (int*)alloc((size_t)E * 4);
    int*   bcnt   = (int*)alloc((NB + 1) * 4);
    int*   bbase  = (int*)alloc((NB + 1) * 4);
    int*   bcur   = (int*)alloc((NB + 1) * 4);
    int*   gstart = (int*)alloc((size_t)(G + 1) * 4);
    float* statsA = (float*)alloc((6 * 256 + 8) * 4);   // per-layer BN sums + agg sums
    float* aggstat= statsA + 6 * 256;
    float* pooled = (float*)alloc((size_t)G * 256 * 4);
    const size_t WPACK = 5 * 384 * 128 + 128 * 192;     // layers 0-4 + layer-5 Wcat
    u16*   whip   = (u16*)alloc(WPACK * 2);
    u16*   wlop   = (u16*)alloc(WPACK * 2);
    u16*   ring0  = (u16*)alloc((size_t)N * 128 * 2);
    u16*   ring1  = (u16*)alloc((size_t)N * 128 * 2);
    u16*   ring2  = (u16*)alloc((size_t)N * 128 * 2);
    u16*   p1     = (u16*)alloc((size_t)N * 128 * 2);
    u16*   p2     = (u16*)alloc((size_t)N * 128 * 2);
    u16*   ring[3] = {ring0, ring1, ring2};
    uint2* esorted = (uint2*)p2;   // alias: dead before first prop2 writes p2
    u16*   zbuf    = p1;           // layer 5: z[N,192] spans p1 (+ start of p2); both dead then

    // ---- CSR build (multisplit) + norm ----
    hipMemsetAsync(bcnt, 0, (NB + 1) * 4, stream);
    hipMemsetAsync(statsA, 0, (6 * 256 + 8) * 4, stream);
    const int nchunk = (E + CHUNK - 1) / CHUNK;
    bucket_hist<<<nchunk, 256, 0, stream>>>(edst, bcnt, E);
    bucket_scan<<<1, 512, 0, stream>>>(bcnt, bbase, bcur);
    bucket_scatter<<<nchunk, 256, 0, stream>>>(esrc, edst, bcur, esorted, E);
    bucket_fill<<<NB, 256, 0, stream>>>(esorted, bbase, rowptr, csr, normv, N, E);

    // ---- x -> bf16 (into ring2; dead before layer 2 writes it) ----
    x2bf_kernel<<<2048, 256, 0, stream>>>(x, ring2, N * 128 / 4);

    // ---- W pack (single launch) ----
    wpack_all<<<(5 * 384 * 128 + 128 * 192 + 255) / 256, 256, 0, stream>>>(
        conv_W, conv_W_last, whip, wlop);

    // ---- graph boundaries ----
    gstart_kernel<<<(N + 255) / 256, 256, 0, stream>>>(seg, gstart, N, G);

    // ---- layers 0-4 (unchanged structure) ----
    const u16* h_in = ring2;
    const int gemm_grid = (N + 127) / 128;
    const float inv_n = 1.f / (float)N;
    for (int l = 0; l < 5; ++l) {
        const u16* whi = whip + (size_t)l * 384 * 128;
        const u16* wlo = wlop + (size_t)l * 384 * 128;
        const float* gamma = bn_g + l * 128;
        const float* beta  = bn_b + l * 128;
        float* stats = statsA + l * 256;
        u16* outbuf = ring[l % 3];

        prop_kernel<<<(N + 3) / 4, 256, 0, stream>>>(h_in, normv, rowptr, csr, p1, N);
        prop_kernel<<<(N + 3) / 4, 256, 0, stream>>>(p1, normv, rowptr, csr, p2, N);

        gemm_mfma<128><<<gemm_grid, 256, 0, stream>>>(h_in, p1, p2, whi, wlo, outbuf,
                                                      stats, N);

        int total4 = N * 128 / 4;
        bool has_skip = (l >= 2);
        const u16* skipb = has_skip ? ring[(l - 2) % 3] : nullptr;
        if (has_skip)
            bn_apply<128, true><<<8192, 256, 0, stream>>>(outbuf, stats, gamma, beta,
                                                          skipb, total4, inv_n);
        else
            bn_apply<128, false><<<8192, 256, 0, stream>>>(outbuf, stats, gamma, beta,
                                                           nullptr, total4, inv_n);
        h_in = outbuf;
    }

    // ---- layer 5 restructured: z = h@[W0|W1|W2]; out_raw = z0 + A(z1 + A z2)
    //      (props on 64-dim rows = half the gather traffic) ----
    {
        const u16* whi5 = whip + (size_t)5 * 384 * 128;
        const u16* wlo5 = wlop + (size_t)5 * 384 * 128;
        u16* u_buf   = ring0;   // outs[3] dead at layer 5
        u16* out_raw = ring2;   // pool reads ring2 (stride 64 now)

        gemm192<<<(N + 63) / 64, 256, 0, stream>>>(h_in, whi5, wlo5, zbuf, N);
        // u = z1 + A z2
        prop64<<<(N + 3) / 4, 256, 0, stream>>>(zbuf + 128, 192, zbuf + 64, 192,
                                                normv, rowptr, csr, u_buf, N);
        // out_raw = z0 + A u
        prop64<<<(N + 3) / 4, 256, 0, stream>>>(u_buf, 64, zbuf, 192,
                                                normv, rowptr, csr, out_raw, N);
        bn_stats64<<<512, 256, 0, stream>>>(out_raw, statsA + 5 * 256, N * 16);
    }

    // ---- pooling (fused layer-5 BN affine + fused agg stats) + head ----
    pool_kernel<<<(G + 3) / 4, 256, 0, stream>>>(ring2, statsA + 5 * 256,
                                                 bn_gl, bn_bl, gstart, pooled, aggstat,
                                                 G, inv_n);
    final_kernel<<<(G + 3) / 4, 256, 0, stream>>>(pooled, aggstat, agg_g, agg_bt,
                                                  aggW, aggb, outW, outb, out, G,
                                                  1.f / (float)(G * 64));
}